// Round 1
// baseline (563.259 us; speedup 1.0000x reference)
//
#include <hip/hip_runtime.h>
#include <hip/hip_bf16.h>
#include <cmath>

// TransformerBlock: N=50000, C=256, H=8, HD=32, M=800000 edges, HID=1024.
// Round 5: LDS-staged GEMM epilogue -> full-cache-line vector stores
// (round-4 fc2 showed WRITE 210MB vs 51MB ideal, 2.6TB/s: scalar stores of
// MFMA column fragments = partial-line writes). bias/extra reads vectorized;
// gelu switched to tanh form (exact erf ~25 VALU x 51M elems).
// Round 6: resubmission of the round-5 artifact unchanged — previous bench
// run failed at the container level (no counters, no timing); no evidence
// to justify a code delta.
// ws: Xb 25.6MB | QKVh 76.8MB | AOb 25.6MB (QKVh+AOb reused as H 102.4MB)
//     | wb 1.6MB | int meta ~3.8MB => ~133.5MB.

#define N_NODES 50000
#define C_DIM 256
#define M_EDGES 800000
#define ATT_SCALE 0.17677669529663687f /* 32^-0.5 */
#define LN_EPS 1e-5f
#define LOG2E 1.4426950408889634f
#define NEG_BIG -3.0e38f

typedef unsigned int uint_t;
typedef unsigned short ushort_t;
typedef short short8 __attribute__((ext_vector_type(8)));
typedef float floatx4 __attribute__((ext_vector_type(4)));

__device__ __forceinline__ ushort_t f2bf(float f) {
  uint_t u = __float_as_uint(f);
  return (ushort_t)((u + 0x7FFFu + ((u >> 16) & 1u)) >> 16);  // RNE
}
__device__ __forceinline__ float bf_even(uint_t u) { return __uint_as_float(u << 16); }
__device__ __forceinline__ float bf_odd(uint_t u) { return __uint_as_float(u & 0xFFFF0000u); }

__device__ __forceinline__ float gelu_tanh(float x) {
  // tanh-form gelu; |diff vs exact erf gelu| <= ~3e-3, within error budget
  const float u = 0.7978845608028654f * (x + 0.044715f * x * x * x);
  const float e = __expf(2.0f * u);
  const float t = 1.0f - 2.0f / (e + 1.0f);
  return 0.5f * x * (1.0f + t);
}

__device__ __forceinline__ void gload16(const void* g, void* l) {
  __builtin_amdgcn_global_load_lds(
      (const __attribute__((address_space(1))) void*)g,
      (__attribute__((address_space(3))) void*)l, 16, 0, 0);
}

// ---------------------------------------------------------------- LayerNorm
__global__ __launch_bounds__(256) void ln_kernel(const float* __restrict__ x,
    const float* __restrict__ g, const float* __restrict__ b,
    ushort_t* __restrict__ y)
{
  __shared__ float red[8];
  const int n = blockIdx.x;
  const int t = threadIdx.x;
  float v = x[(size_t)n * C_DIM + t];
  float s = v, s2 = v * v;
#pragma unroll
  for (int m = 1; m < 64; m <<= 1) {
    s += __shfl_xor(s, m);
    s2 += __shfl_xor(s2, m);
  }
  const int wave = t >> 6;
  if ((t & 63) == 0) { red[wave] = s; red[4 + wave] = s2; }
  __syncthreads();
  s = red[0] + red[1] + red[2] + red[3];
  s2 = red[4] + red[5] + red[6] + red[7];
  const float mean = s * (1.0f / 256.0f);
  const float var = fmaxf(s2 * (1.0f / 256.0f) - mean * mean, 0.0f);
  const float r = rsqrtf(var + LN_EPS);
  y[(size_t)n * C_DIM + t] = f2bf((v - mean) * r * g[t] + b[t]);
}

// ------------------------------------------------- fused fp32->bf16 weights
__global__ void cvt_kernel(const float* __restrict__ s0, const float* __restrict__ s1,
                           const float* __restrict__ s2, const float* __restrict__ s3,
                           ushort_t* __restrict__ dst)
{
  const int i = blockIdx.x * 256 + threadIdx.x;
  // segments: qkv_w 196608 | proj_w 65536 | fc1_w 262144 | fc2_w 262144
  float v;
  if (i < 196608) v = s0[i];
  else if (i < 262144) v = s1[i - 196608];
  else if (i < 524288) v = s2[i - 262144];
  else v = s3[i - 524288];
  dst[i] = f2bf(v);
}

// ---------------------------------------------------------------- MFMA GEMM
// Out[n][j] = sum_k A[n][k]*W[j][k] + bias[j] (+ epilogue). BK=64.
// EPI 0: cols<256 *= ATT_SCALE; bf16 out (qkv)
// EPI 1: + extra[n][j]; fp32 out (proj+skip, fc2+skip)
// EPI 2: tanh-gelu; bf16 out (fc1)
// 128x128 tile, 4 waves -> 64x64 quadrants, 4x4 16x16x32 MFMAs x 2 k-halves.
// K-loop LDS: row-major 128x64 bf16, chunk (r,kc) at kc_lds=kc^(r&7).
// Epilogue: per-wave LDS transpose (9216B/wave) -> float4/ushort8 stores,
// full 128B lines (fixes round-4's 4x write amplification).
template <int EPI>
__global__ __launch_bounds__(256, 2) void mfma_gemm(
    const ushort_t* __restrict__ A, const ushort_t* __restrict__ W,
    const float* __restrict__ bias, const float* __restrict__ extra,
    void* __restrict__ OutV, int Kdim, int Jdim)
{
  __shared__ __align__(16) char smem[36864];  // 32KB staging / 36KB epilogue
  ushort_t* As = (ushort_t*)smem;
  ushort_t* Bs = As + 128 * 64;
  const int t = threadIdx.x;
  const int lane = t & 63;
  const int w = t >> 6;
  const int wm = w & 1;
  const int wn = w >> 1;
  const int rowbase = blockIdx.y * 128;
  const int colbase = blockIdx.x * 128;

  floatx4 acc[4][4] = {};

  int rA[4], kcg[4];
#pragma unroll
  for (int h = 0; h < 4; ++h) {
    const int cidx = h * 256 + w * 64 + lane;
    const int r = cidx >> 3;
    rA[h] = r;
    kcg[h] = (cidx & 7) ^ (r & 7);
  }

  const int rl = lane & 15;
  const int qd = lane >> 4;  // 0..3

  for (int k0 = 0; k0 < Kdim; k0 += 64) {
#pragma unroll
    for (int h = 0; h < 4; ++h) {
      const int r = rA[h];
      int grow = rowbase + r;
      if (grow > N_NODES - 1) grow = N_NODES - 1;  // clamp tail rows
      const int gcol = colbase + r;                // Jdim multiple of 128
      ushort_t* lbase_a = As + (size_t)(h * 256 + w * 64) * 8;
      ushort_t* lbase_b = Bs + (size_t)(h * 256 + w * 64) * 8;
      gload16(A + (size_t)grow * Kdim + k0 + kcg[h] * 8, lbase_a);
      gload16(W + (size_t)gcol * Kdim + k0 + kcg[h] * 8, lbase_b);
    }
    __syncthreads();

#pragma unroll
    for (int h = 0; h < 2; ++h) {
      short8 af[4], bf[4];
#pragma unroll
      for (int tm = 0; tm < 4; ++tm) {
        const int ra = wm * 64 + tm * 16 + rl;
        const int kc = (h * 4 + qd) ^ (ra & 7);
        af[tm] = *(const short8*)(As + ra * 64 + kc * 8);
      }
#pragma unroll
      for (int tn = 0; tn < 4; ++tn) {
        const int rb = wn * 64 + tn * 16 + rl;
        const int kc = (h * 4 + qd) ^ (rb & 7);
        bf[tn] = *(const short8*)(Bs + rb * 64 + kc * 8);
      }
#pragma unroll
      for (int tm = 0; tm < 4; ++tm)
#pragma unroll
        for (int tn = 0; tn < 4; ++tn)
          acc[tm][tn] = __builtin_amdgcn_mfma_f32_16x16x32_bf16(
              af[tm], bf[tn], acc[tm][tn], 0, 0, 0);
    }
    __syncthreads();
  }

  // ---- epilogue: LDS transpose -> full-line vector stores ----
  const int q8 = lane >> 3;  // 0..7 (row-group in read phase)
  const int c8 = lane & 7;   // 0..7 (col quad/oct in read phase)
  if (EPI == 1) {
    float* sc = (float*)smem + w * (64 * 36);  // 64 rows x stride 36 fp32
#pragma unroll
    for (int p = 0; p < 2; ++p) {
      __syncthreads();
#pragma unroll
      for (int th = 0; th < 2; ++th) {
        const int tn = p * 2 + th;
#pragma unroll
        for (int tm = 0; tm < 4; ++tm)
#pragma unroll
          for (int r = 0; r < 4; ++r)
            sc[(tm * 16 + qd * 4 + r) * 36 + th * 16 + rl] = acc[tm][tn][r];
      }
      __syncthreads();
      const int col0 = colbase + wn * 64 + p * 32 + c8 * 4;
      const float4 b4 = *(const float4*)(bias + col0);
#pragma unroll
      for (int it = 0; it < 8; ++it) {
        const int lr = it * 8 + q8;
        const int grow = rowbase + wm * 64 + lr;
        if (grow >= N_NODES) continue;
        float4 v = *(const float4*)(sc + lr * 36 + c8 * 4);
        const float4 e4 = *(const float4*)(extra + (size_t)grow * Jdim + col0);
        v.x += b4.x + e4.x; v.y += b4.y + e4.y;
        v.z += b4.z + e4.z; v.w += b4.w + e4.w;
        *(float4*)((float*)OutV + (size_t)grow * Jdim + col0) = v;
      }
    }
  } else {
    ushort_t* su = (ushort_t*)smem + w * (64 * 72);  // 64 rows x stride 72
#pragma unroll
    for (int tn = 0; tn < 4; ++tn) {
      const int col = colbase + wn * 64 + tn * 16 + rl;
      const float bv = bias[col];
#pragma unroll
      for (int tm = 0; tm < 4; ++tm)
#pragma unroll
        for (int r = 0; r < 4; ++r) {
          float v = acc[tm][tn][r] + bv;
          if (EPI == 0) {
            if (col < 256) v *= ATT_SCALE;
          } else {
            v = gelu_tanh(v);
          }
          su[(tm * 16 + qd * 4 + r) * 72 + tn * 16 + rl] = f2bf(v);
        }
    }
    __syncthreads();
#pragma unroll
    for (int it = 0; it < 8; ++it) {
      const int lr = it * 8 + q8;
      const int grow = rowbase + wm * 64 + lr;
      if (grow >= N_NODES) continue;
      const uint4 v = *(const uint4*)(su + lr * 72 + c8 * 8);
      *(uint4*)((ushort_t*)OutV + (size_t)grow * Jdim + colbase + wn * 64 + c8 * 8) = v;
    }
  }
}

// ---------------------------------------------------------------- edge bucket
__global__ void hist_kernel(const int* __restrict__ idx0, int* __restrict__ counts)
{
  const int m = blockIdx.x * 256 + threadIdx.x;
  if (m < M_EDGES) atomicAdd(&counts[idx0[m]], 1);
}

__global__ __launch_bounds__(256) void scan1_kernel(const int* __restrict__ counts,
    int* __restrict__ offsets, int* __restrict__ bsums)
{
  __shared__ int tmp[256];
  const int t = threadIdx.x;
  const int i = blockIdx.x * 256 + t;
  const int v = (i < N_NODES) ? counts[i] : 0;
  int x = v;
  tmp[t] = x;
  __syncthreads();
#pragma unroll
  for (int off = 1; off < 256; off <<= 1) {
    const int a = (t >= off) ? tmp[t - off] : 0;
    __syncthreads();
    x += a;
    tmp[t] = x;
    __syncthreads();
  }
  if (i < N_NODES) offsets[i] = x - v;
  if (t == 255) bsums[blockIdx.x] = x;
}

__global__ __launch_bounds__(256) void scan2_kernel(int* __restrict__ bsums, int nb)
{
  __shared__ int tmp[256];
  const int t = threadIdx.x;
  const int v = (t < nb) ? bsums[t] : 0;
  int x = v;
  tmp[t] = x;
  __syncthreads();
#pragma unroll
  for (int off = 1; off < 256; off <<= 1) {
    const int a = (t >= off) ? tmp[t - off] : 0;
    __syncthreads();
    x += a;
    tmp[t] = x;
    __syncthreads();
  }
  if (t < nb) bsums[t] = x - v;
}

__global__ void scan3_kernel(int* __restrict__ offsets, const int* __restrict__ bsums)
{
  const int i = blockIdx.x * 256 + threadIdx.x;
  if (i < N_NODES) offsets[i] += bsums[blockIdx.x];
  if (i == 0) offsets[N_NODES] = M_EDGES;
}

__global__ void scatter_kernel(const int* __restrict__ idx0,
    const int* __restrict__ idx1, const int* __restrict__ offsets,
    int* __restrict__ cursor, int* __restrict__ srcs)
{
  const int m = blockIdx.x * 256 + threadIdx.x;
  if (m < M_EDGES) {
    const int n = idx0[m];
    const int p = offsets[n] + atomicAdd(&cursor[n], 1);
    srcs[p] = idx1[m];
  }
}

// ---------------------------------------------------------------- attention
__global__ __launch_bounds__(256) void attn_kernel(
    const ushort_t* __restrict__ QKVh, const int* __restrict__ offsets,
    const int* __restrict__ srcs, ushort_t* __restrict__ AO)
{
  const int node = blockIdx.x * 4 + (threadIdx.x >> 6);
  if (node >= N_NODES) return;
  const int lane = threadIdx.x & 63;
  const int h = lane & 7;
  const int slot = lane >> 3;
  const int start = offsets[node];
  const int end = offsets[node + 1];

  float q[32];
  {
    const uint4* qr = (const uint4*)(QKVh + (size_t)node * 768 + h * 32);
#pragma unroll
    for (int i = 0; i < 4; ++i) {
      const uint4 u = qr[i];
      q[i * 8 + 0] = bf_even(u.x); q[i * 8 + 1] = bf_odd(u.x);
      q[i * 8 + 2] = bf_even(u.y); q[i * 8 + 3] = bf_odd(u.y);
      q[i * 8 + 4] = bf_even(u.z); q[i * 8 + 5] = bf_odd(u.z);
      q[i * 8 + 6] = bf_even(u.w); q[i * 8 + 7] = bf_odd(u.w);
    }
  }

  float m = NEG_BIG, s = 0.f;
  float o[32];
#pragma unroll
  for (int d = 0; d < 32; ++d) o[d] = 0.f;

  for (int e = start + slot; e < end; e += 8) {
    const int sidx = srcs[e];
    const uint4* kr = (const uint4*)(QKVh + (size_t)sidx * 768 + 256 + h * 32);
    float d = 0.f;
#pragma unroll
    for (int i = 0; i < 4; ++i) {
      const uint4 u = kr[i];
      d += q[i * 8 + 0] * bf_even(u.x) + q[i * 8 + 1] * bf_odd(u.x);
      d += q[i * 8 + 2] * bf_even(u.y) + q[i * 8 + 3] * bf_odd(u.y);
      d += q[i * 8 + 4] * bf_even(u.z) + q[i * 8 + 5] * bf_odd(u.z);
      d += q[i * 8 + 6] * bf_even(u.w) + q[i * 8 + 7] * bf_odd(u.w);
    }
    const float l = d * LOG2E;
    const float mn = fmaxf(m, l);
    const float fac = exp2f(m - mn);
    const float wgt = exp2f(l - mn);
    m = mn;
    s = s * fac + wgt;
    const uint4* vr = (const uint4*)(QKVh + (size_t)sidx * 768 + 512 + h * 32);
#pragma unroll
    for (int i = 0; i < 4; ++i) {
      const uint4 u = vr[i];
      o[i * 8 + 0] = o[i * 8 + 0] * fac + wgt * bf_even(u.x);
      o[i * 8 + 1] = o[i * 8 + 1] * fac + wgt * bf_odd(u.x);
      o[i * 8 + 2] = o[i * 8 + 2] * fac + wgt * bf_even(u.y);
      o[i * 8 + 3] = o[i * 8 + 3] * fac + wgt * bf_odd(u.y);
      o[i * 8 + 4] = o[i * 8 + 4] * fac + wgt * bf_even(u.z);
      o[i * 8 + 5] = o[i * 8 + 5] * fac + wgt * bf_odd(u.z);
      o[i * 8 + 6] = o[i * 8 + 6] * fac + wgt * bf_even(u.w);
      o[i * 8 + 7] = o[i * 8 + 7] * fac + wgt * bf_odd(u.w);
    }
  }

  float mx = m;
  mx = fmaxf(mx, __shfl_xor(mx, 8));
  mx = fmaxf(mx, __shfl_xor(mx, 16));
  mx = fmaxf(mx, __shfl_xor(mx, 32));
  const float fac = exp2f(m - mx);
  s *= fac;
#pragma unroll
  for (int d = 0; d < 32; ++d) o[d] *= fac;

  s += __shfl_xor(s, 8);
  s += __shfl_xor(s, 16);
  s += __shfl_xor(s, 32);

  {
    const bool up = (slot & 4) != 0;
#pragma unroll
    for (int i = 0; i < 16; ++i) {
      const float send = up ? o[i] : o[i + 16];
      const float recv = __shfl_xor(send, 32);
      o[i] = (up ? o[i + 16] : o[i]) + recv;
    }
  }
  {
    const bool up = (slot & 2) != 0;
#pragma unroll
    for (int i = 0; i < 8; ++i) {
      const float send = up ? o[i] : o[i + 8];
      const float recv = __shfl_xor(send, 16);
      o[i] = (up ? o[i + 8] : o[i]) + recv;
    }
  }
  {
    const bool up = (slot & 1) != 0;
#pragma unroll
    for (int i = 0; i < 4; ++i) {
      const float send = up ? o[i] : o[i + 4];
      const float recv = __shfl_xor(send, 8);
      o[i] = (up ? o[i + 4] : o[i]) + recv;
    }
  }
  const int dbase = ((slot & 4) ? 16 : 0) + ((slot & 2) ? 8 : 0) +
                    ((slot & 1) ? 4 : 0);
  const float inv = (end > start) ? 1.0f / s : 0.0f;
  ushort4 st;
  st.x = f2bf(o[0] * inv); st.y = f2bf(o[1] * inv);
  st.z = f2bf(o[2] * inv); st.w = f2bf(o[3] * inv);
  *(ushort4*)(AO + (size_t)node * 256 + h * 32 + dbase) = st;
}

// ---------------------------------------------------------------- launch
extern "C" void kernel_launch(void* const* d_in, const int* in_sizes, int n_in,
                              void* d_out, int out_size, void* d_ws,
                              size_t ws_size, hipStream_t stream)
{
  const float* feats  = (const float*)d_in[0];
  const int*   edge   = (const int*)d_in[2];
  const float* ln1_g  = (const float*)d_in[3];
  const float* ln1_b  = (const float*)d_in[4];
  const float* qkv_w  = (const float*)d_in[5];
  const float* qkv_b  = (const float*)d_in[6];
  const float* proj_w = (const float*)d_in[7];
  const float* proj_b = (const float*)d_in[8];
  const float* ln2_g  = (const float*)d_in[9];
  const float* ln2_b  = (const float*)d_in[10];
  const float* fc1_w  = (const float*)d_in[11];
  const float* fc1_b  = (const float*)d_in[12];
  const float* fc2_w  = (const float*)d_in[13];
  const float* fc2_b  = (const float*)d_in[14];
  float* out = (float*)d_out;

  ushort_t* Xb   = (ushort_t*)d_ws;                       // N*256 bf16
  ushort_t* QKVh = Xb + (size_t)N_NODES * 256;            // N*768 bf16
  ushort_t* AOb  = QKVh + (size_t)N_NODES * 768;          // N*256 bf16
  ushort_t* Hb   = QKVh;                                  // N*1024 overlay
  ushort_t* wb   = AOb + (size_t)N_NODES * 256;           // 786432 bf16
  ushort_t* qkv_wb  = wb;
  ushort_t* proj_wb = qkv_wb + 768 * 256;
  ushort_t* fc1_wb  = proj_wb + 256 * 256;
  ushort_t* fc2_wb  = fc1_wb + 1024 * 256;
  int* counts  = (int*)(fc2_wb + 256 * 1024);
  int* cursor  = counts + N_NODES;
  int* offsets = cursor + N_NODES;
  int* srcs    = offsets + N_NODES + 1;
  int* bsums   = srcs + M_EDGES;
  const size_t required = (size_t)((char*)(bsums + 256) - (char*)d_ws);
  if (ws_size < required) {
    hipMemsetAsync(d_out, 0, (size_t)out_size * sizeof(float), stream);
    return;
  }
  const int* idx0 = edge;
  const int* idx1 = edge + M_EDGES;
  const int rowTiles = (N_NODES + 127) / 128;    // 391
  const int scanBlocks = (N_NODES + 255) / 256;  // 196

  hipMemsetAsync(counts, 0, 2 * N_NODES * sizeof(int), stream);
  cvt_kernel<<<786432 / 256, 256, 0, stream>>>(qkv_w, proj_w, fc1_w, fc2_w, wb);

  ln_kernel<<<N_NODES, 256, 0, stream>>>(feats, ln1_g, ln1_b, Xb);
  mfma_gemm<0><<<dim3(768 / 128, rowTiles), 256, 0, stream>>>(
      Xb, qkv_wb, qkv_b, nullptr, QKVh, 256, 768);
  hist_kernel<<<(M_EDGES + 255) / 256, 256, 0, stream>>>(idx0, counts);
  scan1_kernel<<<scanBlocks, 256, 0, stream>>>(counts, offsets, bsums);
  scan2_kernel<<<1, 256, 0, stream>>>(bsums, scanBlocks);
  scan3_kernel<<<scanBlocks, 256, 0, stream>>>(offsets, bsums);
  scatter_kernel<<<(M_EDGES + 255) / 256, 256, 0, stream>>>(idx0, idx1, offsets,
                                                            cursor, srcs);
  attn_kernel<<<N_NODES / 4, 256, 0, stream>>>(QKVh, offsets, srcs, AOb);
  mfma_gemm<1><<<dim3(256 / 128, rowTiles), 256, 0, stream>>>(
      AOb, proj_wb, proj_b, feats, out, 256, 256);
  ln_kernel<<<N_NODES, 256, 0, stream>>>(out, ln2_g, ln2_b, Xb);
  mfma_gemm<2><<<dim3(1024 / 128, rowTiles), 256, 0, stream>>>(
      Xb, fc1_wb, fc1_b, nullptr, Hb, 256, 1024);
  mfma_gemm<1><<<dim3(256 / 128, rowTiles), 256, 0, stream>>>(
      Hb, fc2_wb, fc2_b, out, out, 1024, 256);
}

// Round 2
// 560.140 us; speedup vs baseline: 1.0056x; 1.0056x over previous
//
#include <hip/hip_runtime.h>
#include <hip/hip_bf16.h>
#include <cmath>

// TransformerBlock: N=50000, C=256, H=8, HD=32, M=800000 edges, HID=1024.
// Round 7:
//  * mfma_gemm retiled 128x128 -> 64x256 (BM=64, BN=256, BK=64, acc[2][8]).
//    Theory: GEMMs are fabric-BW-bound on A-panel re-reads across column
//    tiles (BN=128: qkv x6, fc1 x8, fc2 x2 re-reads ~= 870MB total). BN=256
//    halves A re-reads (-307MB) and fixes proj/fc2 grid balance (782 blocks).
//    Same staging swizzle + two-barrier structure (proven correct).
//  * attn_kernel: 2 edges per lane per iteration -> 2x memory-level
//    parallelism on the latency-bound srcs->K/V gather chain; merged online
//    softmax update (one rescale per 2 edges).
//  * ln_kernel: one row per wave, float4 loads, no LDS/barriers.
// ws: Xb 25.6MB | QKVh 76.8MB | AOb 25.6MB (QKVh+AOb reused as H 102.4MB)
//     | wb 1.6MB | int meta ~3.8MB => ~133.5MB.

#define N_NODES 50000
#define C_DIM 256
#define M_EDGES 800000
#define ATT_SCALE 0.17677669529663687f /* 32^-0.5 */
#define LN_EPS 1e-5f
#define LOG2E 1.4426950408889634f
#define NEG_BIG -3.0e38f

typedef unsigned int uint_t;
typedef unsigned short ushort_t;
typedef short short8 __attribute__((ext_vector_type(8)));
typedef float floatx4 __attribute__((ext_vector_type(4)));

__device__ __forceinline__ ushort_t f2bf(float f) {
  uint_t u = __float_as_uint(f);
  return (ushort_t)((u + 0x7FFFu + ((u >> 16) & 1u)) >> 16);  // RNE
}
__device__ __forceinline__ float bf_even(uint_t u) { return __uint_as_float(u << 16); }
__device__ __forceinline__ float bf_odd(uint_t u) { return __uint_as_float(u & 0xFFFF0000u); }

__device__ __forceinline__ float gelu_tanh(float x) {
  // tanh-form gelu; |diff vs exact erf gelu| <= ~3e-3, within error budget
  const float u = 0.7978845608028654f * (x + 0.044715f * x * x * x);
  const float e = __expf(2.0f * u);
  const float t = 1.0f - 2.0f / (e + 1.0f);
  return 0.5f * x * (1.0f + t);
}

__device__ __forceinline__ void gload16(const void* g, void* l) {
  __builtin_amdgcn_global_load_lds(
      (const __attribute__((address_space(1))) void*)g,
      (__attribute__((address_space(3))) void*)l, 16, 0, 0);
}

// ---------------------------------------------------------------- LayerNorm
// One row per wave: 64 lanes x float4 = 256 floats. No LDS, no barriers.
__global__ __launch_bounds__(256) void ln_kernel(const float* __restrict__ x,
    const float* __restrict__ g, const float* __restrict__ b,
    ushort_t* __restrict__ y)
{
  const int row = blockIdx.x * 4 + (threadIdx.x >> 6);
  const int lane = threadIdx.x & 63;
  const float4 v = *(const float4*)(x + (size_t)row * C_DIM + lane * 4);
  float s = v.x + v.y + v.z + v.w;
  float s2 = v.x * v.x + v.y * v.y + v.z * v.z + v.w * v.w;
#pragma unroll
  for (int m = 1; m < 64; m <<= 1) {
    s += __shfl_xor(s, m);
    s2 += __shfl_xor(s2, m);
  }
  const float mean = s * (1.0f / 256.0f);
  const float var = fmaxf(s2 * (1.0f / 256.0f) - mean * mean, 0.0f);
  const float r = rsqrtf(var + LN_EPS);
  const float4 g4 = *(const float4*)(g + lane * 4);
  const float4 b4 = *(const float4*)(b + lane * 4);
  ushort4 o;
  o.x = f2bf((v.x - mean) * r * g4.x + b4.x);
  o.y = f2bf((v.y - mean) * r * g4.y + b4.y);
  o.z = f2bf((v.z - mean) * r * g4.z + b4.z);
  o.w = f2bf((v.w - mean) * r * g4.w + b4.w);
  *(ushort4*)(y + (size_t)row * C_DIM + lane * 4) = o;
}

// ------------------------------------------------- fused fp32->bf16 weights
__global__ void cvt_kernel(const float* __restrict__ s0, const float* __restrict__ s1,
                           const float* __restrict__ s2, const float* __restrict__ s3,
                           ushort_t* __restrict__ dst)
{
  const int i = blockIdx.x * 256 + threadIdx.x;
  // segments: qkv_w 196608 | proj_w 65536 | fc1_w 262144 | fc2_w 262144
  float v;
  if (i < 196608) v = s0[i];
  else if (i < 262144) v = s1[i - 196608];
  else if (i < 524288) v = s2[i - 262144];
  else v = s3[i - 524288];
  dst[i] = f2bf(v);
}

// ---------------------------------------------------------------- MFMA GEMM
// Out[n][j] = sum_k A[n][k]*W[j][k] + bias[j] (+ epilogue). BK=64.
// EPI 0: cols<256 *= ATT_SCALE; bf16 out (qkv)
// EPI 1: + extra[n][j]; fp32 out (proj+skip, fc2+skip)
// EPI 2: tanh-gelu; bf16 out (fc1)
// 64x256 tile, 4 waves -> 32x128 quadrants, 2x8 16x16x32 MFMAs x 2 k-halves.
// Halves A-panel re-fetch vs 128x128 (fewer column tiles per GEMM).
// K-loop LDS: A 64x64 + B 256x64 bf16 row-major, chunk (r,kc) at kc^(r&7).
// Epilogue: per-wave LDS transpose (8.5KB/wave) -> float4/ushort8 stores.
template <int EPI>
__global__ __launch_bounds__(256, 2) void mfma_gemm(
    const ushort_t* __restrict__ A, const ushort_t* __restrict__ W,
    const float* __restrict__ bias, const float* __restrict__ extra,
    void* __restrict__ OutV, int Kdim, int Jdim)
{
  __shared__ __align__(16) char smem[40960];  // A 8KB + B 32KB staging
  ushort_t* As = (ushort_t*)smem;
  ushort_t* Bs = As + 64 * 64;                // 4096 ushorts in
  const int t = threadIdx.x;
  const int lane = t & 63;
  const int w = t >> 6;
  const int wm = w & 1;    // row half (32 rows)
  const int wn = w >> 1;   // col half (128 cols)
  const int rowbase = blockIdx.y * 64;
  const int colbase = blockIdx.x * 256;

  floatx4 acc[2][8] = {};

  // staging geometry: linear chunk cidx = h*256 + base; row = h*32 + rbase.
  const int base = w * 64 + lane;            // 0..255
  const int rbase = base >> 3;               // 0..31
  const int kcs = (base & 7) ^ (rbase & 7);  // same for all h (h*32 % 8 == 0)

  const int rl = lane & 15;
  const int qd = lane >> 4;  // 0..3

  for (int k0 = 0; k0 < Kdim; k0 += 64) {
#pragma unroll
    for (int h = 0; h < 2; ++h) {            // A tile: 64 rows
      int grow = rowbase + h * 32 + rbase;
      if (grow > N_NODES - 1) grow = N_NODES - 1;  // clamp tail rows
      gload16(A + (size_t)grow * Kdim + k0 + kcs * 8,
              As + (h * 256 + w * 64) * 8);
    }
#pragma unroll
    for (int h = 0; h < 8; ++h) {            // B tile: 256 rows (cols of Out)
      const int gcol = colbase + h * 32 + rbase;   // Jdim multiple of 256
      gload16(W + (size_t)gcol * Kdim + k0 + kcs * 8,
              Bs + (h * 256 + w * 64) * 8);
    }
    __syncthreads();

#pragma unroll
    for (int h = 0; h < 2; ++h) {
      short8 af[2], bf[8];
#pragma unroll
      for (int tm = 0; tm < 2; ++tm) {
        const int ra = wm * 32 + tm * 16 + rl;
        const int kc = (h * 4 + qd) ^ (ra & 7);
        af[tm] = *(const short8*)(As + ra * 64 + kc * 8);
      }
#pragma unroll
      for (int tn = 0; tn < 8; ++tn) {
        const int rb = wn * 128 + tn * 16 + rl;
        const int kc = (h * 4 + qd) ^ (rb & 7);
        bf[tn] = *(const short8*)(Bs + rb * 64 + kc * 8);
      }
#pragma unroll
      for (int tm = 0; tm < 2; ++tm)
#pragma unroll
        for (int tn = 0; tn < 8; ++tn)
          acc[tm][tn] = __builtin_amdgcn_mfma_f32_16x16x32_bf16(
              af[tm], bf[tn], acc[tm][tn], 0, 0, 0);
    }
    __syncthreads();
  }

  // ---- epilogue: LDS transpose -> full-line vector stores ----
  const int rr = lane >> 4;        // 0..3 (row group in read phase)
  if (EPI == 1) {
    float* sc = (float*)smem + w * (32 * 68);  // 32 rows x stride 68 fp32
    const int c4 = (lane & 15) * 4;            // 0..60
#pragma unroll
    for (int p = 0; p < 2; ++p) {
      __syncthreads();
#pragma unroll
      for (int th = 0; th < 4; ++th) {
        const int tn = p * 4 + th;
#pragma unroll
        for (int tm = 0; tm < 2; ++tm)
#pragma unroll
          for (int r = 0; r < 4; ++r)
            sc[(tm * 16 + qd * 4 + r) * 68 + th * 16 + rl] = acc[tm][tn][r];
      }
      __syncthreads();
      const int col0 = colbase + wn * 128 + p * 64 + c4;
      const float4 b4 = *(const float4*)(bias + col0);
#pragma unroll
      for (int it = 0; it < 8; ++it) {
        const int lr = it * 4 + rr;
        const int grow = rowbase + wm * 32 + lr;
        if (grow >= N_NODES) continue;
        float4 v = *(const float4*)(sc + lr * 68 + c4);
        const float4 e4 = *(const float4*)(extra + (size_t)grow * Jdim + col0);
        v.x += b4.x + e4.x; v.y += b4.y + e4.y;
        v.z += b4.z + e4.z; v.w += b4.w + e4.w;
        *(float4*)((float*)OutV + (size_t)grow * Jdim + col0) = v;
      }
    }
  } else {
    __syncthreads();
    ushort_t* su = (ushort_t*)smem + w * (32 * 136);  // 32 rows x stride 136
#pragma unroll
    for (int tn = 0; tn < 8; ++tn) {
      const int col = colbase + wn * 128 + tn * 16 + rl;
      const float bv = bias[col];
#pragma unroll
      for (int tm = 0; tm < 2; ++tm)
#pragma unroll
        for (int r = 0; r < 4; ++r) {
          float v = acc[tm][tn][r] + bv;
          if (EPI == 0) {
            if (col < 256) v *= ATT_SCALE;
          } else {
            v = gelu_tanh(v);
          }
          su[(tm * 16 + qd * 4 + r) * 136 + tn * 16 + rl] = f2bf(v);
        }
    }
    __syncthreads();
    const int c8 = (lane & 15) * 8;
#pragma unroll
    for (int it = 0; it < 8; ++it) {
      const int lr = it * 4 + rr;
      const int grow = rowbase + wm * 32 + lr;
      if (grow >= N_NODES) continue;
      const uint4 v = *(const uint4*)(su + lr * 136 + c8);
      *(uint4*)((ushort_t*)OutV + (size_t)grow * Jdim + colbase + wn * 128 + c8) = v;
    }
  }
}

// ---------------------------------------------------------------- edge bucket
__global__ void hist_kernel(const int* __restrict__ idx0, int* __restrict__ counts)
{
  const int m = blockIdx.x * 256 + threadIdx.x;
  if (m < M_EDGES) atomicAdd(&counts[idx0[m]], 1);
}

__global__ __launch_bounds__(256) void scan1_kernel(const int* __restrict__ counts,
    int* __restrict__ offsets, int* __restrict__ bsums)
{
  __shared__ int tmp[256];
  const int t = threadIdx.x;
  const int i = blockIdx.x * 256 + t;
  const int v = (i < N_NODES) ? counts[i] : 0;
  int x = v;
  tmp[t] = x;
  __syncthreads();
#pragma unroll
  for (int off = 1; off < 256; off <<= 1) {
    const int a = (t >= off) ? tmp[t - off] : 0;
    __syncthreads();
    x += a;
    tmp[t] = x;
    __syncthreads();
  }
  if (i < N_NODES) offsets[i] = x - v;
  if (t == 255) bsums[blockIdx.x] = x;
}

__global__ __launch_bounds__(256) void scan2_kernel(int* __restrict__ bsums, int nb)
{
  __shared__ int tmp[256];
  const int t = threadIdx.x;
  const int v = (t < nb) ? bsums[t] : 0;
  int x = v;
  tmp[t] = x;
  __syncthreads();
#pragma unroll
  for (int off = 1; off < 256; off <<= 1) {
    const int a = (t >= off) ? tmp[t - off] : 0;
    __syncthreads();
    x += a;
    tmp[t] = x;
    __syncthreads();
  }
  if (t < nb) bsums[t] = x - v;
}

__global__ void scan3_kernel(int* __restrict__ offsets, const int* __restrict__ bsums)
{
  const int i = blockIdx.x * 256 + threadIdx.x;
  if (i < N_NODES) offsets[i] += bsums[blockIdx.x];
  if (i == 0) offsets[N_NODES] = M_EDGES;
}

__global__ void scatter_kernel(const int* __restrict__ idx0,
    const int* __restrict__ idx1, const int* __restrict__ offsets,
    int* __restrict__ cursor, int* __restrict__ srcs)
{
  const int m = blockIdx.x * 256 + threadIdx.x;
  if (m < M_EDGES) {
    const int n = idx0[m];
    const int p = offsets[n] + atomicAdd(&cursor[n], 1);
    srcs[p] = idx1[m];
  }
}

// ---------------------------------------------------------------- attention
// 2 edges per lane per iteration: both srcs + both K rows + both V rows
// issued together -> 2x memory-level parallelism on the gather chain.
__global__ __launch_bounds__(256) void attn_kernel(
    const ushort_t* __restrict__ QKVh, const int* __restrict__ offsets,
    const int* __restrict__ srcs, ushort_t* __restrict__ AO)
{
  const int node = blockIdx.x * 4 + (threadIdx.x >> 6);
  if (node >= N_NODES) return;
  const int lane = threadIdx.x & 63;
  const int h = lane & 7;
  const int slot = lane >> 3;
  const int start = offsets[node];
  const int end = offsets[node + 1];

  float q[32];
  {
    const uint4* qr = (const uint4*)(QKVh + (size_t)node * 768 + h * 32);
#pragma unroll
    for (int i = 0; i < 4; ++i) {
      const uint4 u = qr[i];
      q[i * 8 + 0] = bf_even(u.x); q[i * 8 + 1] = bf_odd(u.x);
      q[i * 8 + 2] = bf_even(u.y); q[i * 8 + 3] = bf_odd(u.y);
      q[i * 8 + 4] = bf_even(u.z); q[i * 8 + 5] = bf_odd(u.z);
      q[i * 8 + 6] = bf_even(u.w); q[i * 8 + 7] = bf_odd(u.w);
    }
  }

  float m = NEG_BIG, s = 0.f;
  float o[32];
#pragma unroll
  for (int d = 0; d < 32; ++d) o[d] = 0.f;

  for (int e = start + slot; e < end; e += 16) {
    const bool has1 = (e + 8) < end;
    const int s0i = srcs[e];
    const int s1i = has1 ? srcs[e + 8] : s0i;
    const uint4* k0p = (const uint4*)(QKVh + (size_t)s0i * 768 + 256 + h * 32);
    const uint4* k1p = (const uint4*)(QKVh + (size_t)s1i * 768 + 256 + h * 32);
    const uint4* v0p = (const uint4*)(QKVh + (size_t)s0i * 768 + 512 + h * 32);
    const uint4* v1p = (const uint4*)(QKVh + (size_t)s1i * 768 + 512 + h * 32);
    uint4 ka[4], kb[4], va[4], vb[4];
#pragma unroll
    for (int i = 0; i < 4; ++i) {
      ka[i] = k0p[i]; kb[i] = k1p[i];
      va[i] = v0p[i]; vb[i] = v1p[i];
    }
    float d0 = 0.f, d1 = 0.f;
#pragma unroll
    for (int i = 0; i < 4; ++i) {
      const uint4 u = ka[i];
      d0 += q[i * 8 + 0] * bf_even(u.x) + q[i * 8 + 1] * bf_odd(u.x);
      d0 += q[i * 8 + 2] * bf_even(u.y) + q[i * 8 + 3] * bf_odd(u.y);
      d0 += q[i * 8 + 4] * bf_even(u.z) + q[i * 8 + 5] * bf_odd(u.z);
      d0 += q[i * 8 + 6] * bf_even(u.w) + q[i * 8 + 7] * bf_odd(u.w);
      const uint4 x = kb[i];
      d1 += q[i * 8 + 0] * bf_even(x.x) + q[i * 8 + 1] * bf_odd(x.x);
      d1 += q[i * 8 + 2] * bf_even(x.y) + q[i * 8 + 3] * bf_odd(x.y);
      d1 += q[i * 8 + 4] * bf_even(x.z) + q[i * 8 + 5] * bf_odd(x.z);
      d1 += q[i * 8 + 6] * bf_even(x.w) + q[i * 8 + 7] * bf_odd(x.w);
    }
    const float l0 = d0 * LOG2E;
    const float l1 = has1 ? d1 * LOG2E : NEG_BIG;
    const float mn = fmaxf(fmaxf(m, l0), l1);
    const float fac = exp2f(m - mn);
    const float w0 = exp2f(l0 - mn);
    const float w1 = has1 ? exp2f(l1 - mn) : 0.f;
    m = mn;
    s = s * fac + w0 + w1;
#pragma unroll
    for (int i = 0; i < 4; ++i) {
      const uint4 ua = va[i];
      const uint4 ub = vb[i];
      o[i * 8 + 0] = o[i * 8 + 0] * fac + w0 * bf_even(ua.x) + w1 * bf_even(ub.x);
      o[i * 8 + 1] = o[i * 8 + 1] * fac + w0 * bf_odd(ua.x)  + w1 * bf_odd(ub.x);
      o[i * 8 + 2] = o[i * 8 + 2] * fac + w0 * bf_even(ua.y) + w1 * bf_even(ub.y);
      o[i * 8 + 3] = o[i * 8 + 3] * fac + w0 * bf_odd(ua.y)  + w1 * bf_odd(ub.y);
      o[i * 8 + 4] = o[i * 8 + 4] * fac + w0 * bf_even(ua.z) + w1 * bf_even(ub.z);
      o[i * 8 + 5] = o[i * 8 + 5] * fac + w0 * bf_odd(ua.z)  + w1 * bf_odd(ub.z);
      o[i * 8 + 6] = o[i * 8 + 6] * fac + w0 * bf_even(ua.w) + w1 * bf_even(ub.w);
      o[i * 8 + 7] = o[i * 8 + 7] * fac + w0 * bf_odd(ua.w)  + w1 * bf_odd(ub.w);
    }
  }

  float mx = m;
  mx = fmaxf(mx, __shfl_xor(mx, 8));
  mx = fmaxf(mx, __shfl_xor(mx, 16));
  mx = fmaxf(mx, __shfl_xor(mx, 32));
  const float fac = exp2f(m - mx);
  s *= fac;
#pragma unroll
  for (int d = 0; d < 32; ++d) o[d] *= fac;

  s += __shfl_xor(s, 8);
  s += __shfl_xor(s, 16);
  s += __shfl_xor(s, 32);

  {
    const bool up = (slot & 4) != 0;
#pragma unroll
    for (int i = 0; i < 16; ++i) {
      const float send = up ? o[i] : o[i + 16];
      const float recv = __shfl_xor(send, 32);
      o[i] = (up ? o[i + 16] : o[i]) + recv;
    }
  }
  {
    const bool up = (slot & 2) != 0;
#pragma unroll
    for (int i = 0; i < 8; ++i) {
      const float send = up ? o[i] : o[i + 8];
      const float recv = __shfl_xor(send, 16);
      o[i] = (up ? o[i + 8] : o[i]) + recv;
    }
  }
  {
    const bool up = (slot & 1) != 0;
#pragma unroll
    for (int i = 0; i < 4; ++i) {
      const float send = up ? o[i] : o[i + 4];
      const float recv = __shfl_xor(send, 8);
      o[i] = (up ? o[i + 4] : o[i]) + recv;
    }
  }
  const int dbase = ((slot & 4) ? 16 : 0) + ((slot & 2) ? 8 : 0) +
                    ((slot & 1) ? 4 : 0);
  const float inv = (end > start) ? 1.0f / s : 0.0f;
  ushort4 st;
  st.x = f2bf(o[0] * inv); st.y = f2bf(o[1] * inv);
  st.z = f2bf(o[2] * inv); st.w = f2bf(o[3] * inv);
  *(ushort4*)(AO + (size_t)node * 256 + h * 32 + dbase) = st;
}

// ---------------------------------------------------------------- launch
extern "C" void kernel_launch(void* const* d_in, const int* in_sizes, int n_in,
                              void* d_out, int out_size, void* d_ws,
                              size_t ws_size, hipStream_t stream)
{
  const float* feats  = (const float*)d_in[0];
  const int*   edge   = (const int*)d_in[2];
  const float* ln1_g  = (const float*)d_in[3];
  const float* ln1_b  = (const float*)d_in[4];
  const float* qkv_w  = (const float*)d_in[5];
  const float* qkv_b  = (const float*)d_in[6];
  const float* proj_w = (const float*)d_in[7];
  const float* proj_b = (const float*)d_in[8];
  const float* ln2_g  = (const float*)d_in[9];
  const float* ln2_b  = (const float*)d_in[10];
  const float* fc1_w  = (const float*)d_in[11];
  const float* fc1_b  = (const float*)d_in[12];
  const float* fc2_w  = (const float*)d_in[13];
  const float* fc2_b  = (const float*)d_in[14];
  float* out = (float*)d_out;

  ushort_t* Xb   = (ushort_t*)d_ws;                       // N*256 bf16
  ushort_t* QKVh = Xb + (size_t)N_NODES * 256;            // N*768 bf16
  ushort_t* AOb  = QKVh + (size_t)N_NODES * 768;          // N*256 bf16
  ushort_t* Hb   = QKVh;                                  // N*1024 overlay
  ushort_t* wb   = AOb + (size_t)N_NODES * 256;           // 786432 bf16
  ushort_t* qkv_wb  = wb;
  ushort_t* proj_wb = qkv_wb + 768 * 256;
  ushort_t* fc1_wb  = proj_wb + 256 * 256;
  ushort_t* fc2_wb  = fc1_wb + 1024 * 256;
  int* counts  = (int*)(fc2_wb + 256 * 1024);
  int* cursor  = counts + N_NODES;
  int* offsets = cursor + N_NODES;
  int* srcs    = offsets + N_NODES + 1;
  int* bsums   = srcs + M_EDGES;
  const size_t required = (size_t)((char*)(bsums + 256) - (char*)d_ws);
  if (ws_size < required) {
    hipMemsetAsync(d_out, 0, (size_t)out_size * sizeof(float), stream);
    return;
  }
  const int* idx0 = edge;
  const int* idx1 = edge + M_EDGES;
  const int rowTiles = (N_NODES + 63) / 64;      // 782
  const int scanBlocks = (N_NODES + 255) / 256;  // 196

  hipMemsetAsync(counts, 0, 2 * N_NODES * sizeof(int), stream);
  cvt_kernel<<<786432 / 256, 256, 0, stream>>>(qkv_w, proj_w, fc1_w, fc2_w, wb);

  ln_kernel<<<N_NODES / 4, 256, 0, stream>>>(feats, ln1_g, ln1_b, Xb);
  mfma_gemm<0><<<dim3(768 / 256, rowTiles), 256, 0, stream>>>(
      Xb, qkv_wb, qkv_b, nullptr, QKVh, 256, 768);
  hist_kernel<<<(M_EDGES + 255) / 256, 256, 0, stream>>>(idx0, counts);
  scan1_kernel<<<scanBlocks, 256, 0, stream>>>(counts, offsets, bsums);
  scan2_kernel<<<1, 256, 0, stream>>>(bsums, scanBlocks);
  scan3_kernel<<<scanBlocks, 256, 0, stream>>>(offsets, bsums);
  scatter_kernel<<<(M_EDGES + 255) / 256, 256, 0, stream>>>(idx0, idx1, offsets,
                                                            cursor, srcs);
  attn_kernel<<<N_NODES / 4, 256, 0, stream>>>(QKVh, offsets, srcs, AOb);
  mfma_gemm<1><<<dim3(256 / 256, rowTiles), 256, 0, stream>>>(
      AOb, proj_wb, proj_b, feats, out, 256, 256);
  ln_kernel<<<N_NODES / 4, 256, 0, stream>>>(out, ln2_g, ln2_b, Xb);
  mfma_gemm<2><<<dim3(1024 / 256, rowTiles), 256, 0, stream>>>(
      Xb, fc1_wb, fc1_b, nullptr, Hb, 256, 1024);
  mfma_gemm<1><<<dim3(256 / 256, rowTiles), 256, 0, stream>>>(
      Hb, fc2_wb, fc2_b, out, out, 1024, 256);
}

// Round 3
// 554.643 us; speedup vs baseline: 1.0155x; 1.0099x over previous
//
#include <hip/hip_runtime.h>
#include <hip/hip_bf16.h>
#include <cmath>

// TransformerBlock: N=50000, C=256, H=8, HD=32, M=800000 edges, HID=1024.
// Round 8:
//  * attn_kernel restructured: 32 lanes cooperatively read one edge's full
//    512B K/V row (contiguous uint4 per lane) instead of 8 head-lanes each
//    grabbing 64B strided slices. Round-7 evidence: per-load-inst 64 distinct
//    cache lines -> L1 line-transaction bound (~105us model vs 119us meas).
//    New layout: 1 inst = 16 lines (2 edges x 8 contiguous). Lane l<32 holds
//    8 dims of head l>>2; dot closes with 2 intra-quad shfl_xor; two wave
//    halves process alternating edges (own online softmax), merged at end
//    via shfl_xor(32). State: q 4 + o 8 regs -> VGPR ~45, occupancy back to
//    8 waves/SIMD (round-7 regression was the 64-VGPR cliff: 68 VGPR -> 27%).
//  * mfma_gemm: __launch_bounds__(256,3) -> 3 blocks/CU (LDS 120KB fits);
//    more waves to hide the per-K-step barrier drain.
// ws: Xb 25.6MB | QKVh 76.8MB | AOb 25.6MB (QKVh+AOb reused as H 102.4MB)
//     | wb 1.6MB | int meta ~3.8MB => ~133.5MB.

#define N_NODES 50000
#define C_DIM 256
#define M_EDGES 800000
#define ATT_SCALE 0.17677669529663687f /* 32^-0.5 */
#define LN_EPS 1e-5f
#define LOG2E 1.4426950408889634f
#define NEG_BIG -3.0e38f

typedef unsigned int uint_t;
typedef unsigned short ushort_t;
typedef short short8 __attribute__((ext_vector_type(8)));
typedef float floatx4 __attribute__((ext_vector_type(4)));

__device__ __forceinline__ ushort_t f2bf(float f) {
  uint_t u = __float_as_uint(f);
  return (ushort_t)((u + 0x7FFFu + ((u >> 16) & 1u)) >> 16);  // RNE
}
__device__ __forceinline__ float bf_even(uint_t u) { return __uint_as_float(u << 16); }
__device__ __forceinline__ float bf_odd(uint_t u) { return __uint_as_float(u & 0xFFFF0000u); }

__device__ __forceinline__ float gelu_tanh(float x) {
  // tanh-form gelu; |diff vs exact erf gelu| <= ~3e-3, within error budget
  const float u = 0.7978845608028654f * (x + 0.044715f * x * x * x);
  const float e = __expf(2.0f * u);
  const float t = 1.0f - 2.0f / (e + 1.0f);
  return 0.5f * x * (1.0f + t);
}

__device__ __forceinline__ void gload16(const void* g, void* l) {
  __builtin_amdgcn_global_load_lds(
      (const __attribute__((address_space(1))) void*)g,
      (__attribute__((address_space(3))) void*)l, 16, 0, 0);
}

// ---------------------------------------------------------------- LayerNorm
// One row per wave: 64 lanes x float4 = 256 floats. No LDS, no barriers.
__global__ __launch_bounds__(256) void ln_kernel(const float* __restrict__ x,
    const float* __restrict__ g, const float* __restrict__ b,
    ushort_t* __restrict__ y)
{
  const int row = blockIdx.x * 4 + (threadIdx.x >> 6);
  const int lane = threadIdx.x & 63;
  const float4 v = *(const float4*)(x + (size_t)row * C_DIM + lane * 4);
  float s = v.x + v.y + v.z + v.w;
  float s2 = v.x * v.x + v.y * v.y + v.z * v.z + v.w * v.w;
#pragma unroll
  for (int m = 1; m < 64; m <<= 1) {
    s += __shfl_xor(s, m);
    s2 += __shfl_xor(s2, m);
  }
  const float mean = s * (1.0f / 256.0f);
  const float var = fmaxf(s2 * (1.0f / 256.0f) - mean * mean, 0.0f);
  const float r = rsqrtf(var + LN_EPS);
  const float4 g4 = *(const float4*)(g + lane * 4);
  const float4 b4 = *(const float4*)(b + lane * 4);
  ushort4 o;
  o.x = f2bf((v.x - mean) * r * g4.x + b4.x);
  o.y = f2bf((v.y - mean) * r * g4.y + b4.y);
  o.z = f2bf((v.z - mean) * r * g4.z + b4.z);
  o.w = f2bf((v.w - mean) * r * g4.w + b4.w);
  *(ushort4*)(y + (size_t)row * C_DIM + lane * 4) = o;
}

// ------------------------------------------------- fused fp32->bf16 weights
__global__ void cvt_kernel(const float* __restrict__ s0, const float* __restrict__ s1,
                           const float* __restrict__ s2, const float* __restrict__ s3,
                           ushort_t* __restrict__ dst)
{
  const int i = blockIdx.x * 256 + threadIdx.x;
  // segments: qkv_w 196608 | proj_w 65536 | fc1_w 262144 | fc2_w 262144
  float v;
  if (i < 196608) v = s0[i];
  else if (i < 262144) v = s1[i - 196608];
  else if (i < 524288) v = s2[i - 262144];
  else v = s3[i - 524288];
  dst[i] = f2bf(v);
}

// ---------------------------------------------------------------- MFMA GEMM
// Out[n][j] = sum_k A[n][k]*W[j][k] + bias[j] (+ epilogue). BK=64.
// EPI 0: cols<256 *= ATT_SCALE; bf16 out (qkv)
// EPI 1: + extra[n][j]; fp32 out (proj+skip, fc2+skip)
// EPI 2: tanh-gelu; bf16 out (fc1)
// 64x256 tile, 4 waves -> 32x128 quadrants, 2x8 16x16x32 MFMAs x 2 k-halves.
// K-loop LDS: A 64x64 + B 256x64 bf16 row-major, chunk (r,kc) at kc^(r&7).
// Epilogue: per-wave LDS transpose (8.5KB/wave) -> float4/ushort8 stores.
template <int EPI>
__global__ __launch_bounds__(256, 3) void mfma_gemm(
    const ushort_t* __restrict__ A, const ushort_t* __restrict__ W,
    const float* __restrict__ bias, const float* __restrict__ extra,
    void* __restrict__ OutV, int Kdim, int Jdim)
{
  __shared__ __align__(16) char smem[40960];  // A 8KB + B 32KB staging
  ushort_t* As = (ushort_t*)smem;
  ushort_t* Bs = As + 64 * 64;                // 4096 ushorts in
  const int t = threadIdx.x;
  const int lane = t & 63;
  const int w = t >> 6;
  const int wm = w & 1;    // row half (32 rows)
  const int wn = w >> 1;   // col half (128 cols)
  const int rowbase = blockIdx.y * 64;
  const int colbase = blockIdx.x * 256;

  floatx4 acc[2][8] = {};

  // staging geometry: linear chunk cidx = h*256 + base; row = h*32 + rbase.
  const int base = w * 64 + lane;            // 0..255
  const int rbase = base >> 3;               // 0..31
  const int kcs = (base & 7) ^ (rbase & 7);  // same for all h (h*32 % 8 == 0)

  const int rl = lane & 15;
  const int qd = lane >> 4;  // 0..3

  for (int k0 = 0; k0 < Kdim; k0 += 64) {
#pragma unroll
    for (int h = 0; h < 2; ++h) {            // A tile: 64 rows
      int grow = rowbase + h * 32 + rbase;
      if (grow > N_NODES - 1) grow = N_NODES - 1;  // clamp tail rows
      gload16(A + (size_t)grow * Kdim + k0 + kcs * 8,
              As + (h * 256 + w * 64) * 8);
    }
#pragma unroll
    for (int h = 0; h < 8; ++h) {            // B tile: 256 rows (cols of Out)
      const int gcol = colbase + h * 32 + rbase;   // Jdim multiple of 256
      gload16(W + (size_t)gcol * Kdim + k0 + kcs * 8,
              Bs + (h * 256 + w * 64) * 8);
    }
    __syncthreads();

#pragma unroll
    for (int h = 0; h < 2; ++h) {
      short8 af[2], bf[8];
#pragma unroll
      for (int tm = 0; tm < 2; ++tm) {
        const int ra = wm * 32 + tm * 16 + rl;
        const int kc = (h * 4 + qd) ^ (ra & 7);
        af[tm] = *(const short8*)(As + ra * 64 + kc * 8);
      }
#pragma unroll
      for (int tn = 0; tn < 8; ++tn) {
        const int rb = wn * 128 + tn * 16 + rl;
        const int kc = (h * 4 + qd) ^ (rb & 7);
        bf[tn] = *(const short8*)(Bs + rb * 64 + kc * 8);
      }
#pragma unroll
      for (int tm = 0; tm < 2; ++tm)
#pragma unroll
        for (int tn = 0; tn < 8; ++tn)
          acc[tm][tn] = __builtin_amdgcn_mfma_f32_16x16x32_bf16(
              af[tm], bf[tn], acc[tm][tn], 0, 0, 0);
    }
    __syncthreads();
  }

  // ---- epilogue: LDS transpose -> full-line vector stores ----
  const int rr = lane >> 4;        // 0..3 (row group in read phase)
  if (EPI == 1) {
    float* sc = (float*)smem + w * (32 * 68);  // 32 rows x stride 68 fp32
    const int c4 = (lane & 15) * 4;            // 0..60
#pragma unroll
    for (int p = 0; p < 2; ++p) {
      __syncthreads();
#pragma unroll
      for (int th = 0; th < 4; ++th) {
        const int tn = p * 4 + th;
#pragma unroll
        for (int tm = 0; tm < 2; ++tm)
#pragma unroll
          for (int r = 0; r < 4; ++r)
            sc[(tm * 16 + qd * 4 + r) * 68 + th * 16 + rl] = acc[tm][tn][r];
      }
      __syncthreads();
      const int col0 = colbase + wn * 128 + p * 64 + c4;
      const float4 b4 = *(const float4*)(bias + col0);
#pragma unroll
      for (int it = 0; it < 8; ++it) {
        const int lr = it * 4 + rr;
        const int grow = rowbase + wm * 32 + lr;
        if (grow >= N_NODES) continue;
        float4 v = *(const float4*)(sc + lr * 68 + c4);
        const float4 e4 = *(const float4*)(extra + (size_t)grow * Jdim + col0);
        v.x += b4.x + e4.x; v.y += b4.y + e4.y;
        v.z += b4.z + e4.z; v.w += b4.w + e4.w;
        *(float4*)((float*)OutV + (size_t)grow * Jdim + col0) = v;
      }
    }
  } else {
    __syncthreads();
    ushort_t* su = (ushort_t*)smem + w * (32 * 136);  // 32 rows x stride 136
#pragma unroll
    for (int tn = 0; tn < 8; ++tn) {
      const int col = colbase + wn * 128 + tn * 16 + rl;
      const float bv = bias[col];
#pragma unroll
      for (int tm = 0; tm < 2; ++tm)
#pragma unroll
        for (int r = 0; r < 4; ++r) {
          float v = acc[tm][tn][r] + bv;
          if (EPI == 0) {
            if (col < 256) v *= ATT_SCALE;
          } else {
            v = gelu_tanh(v);
          }
          su[(tm * 16 + qd * 4 + r) * 136 + tn * 16 + rl] = f2bf(v);
        }
    }
    __syncthreads();
    const int c8 = (lane & 15) * 8;
#pragma unroll
    for (int it = 0; it < 8; ++it) {
      const int lr = it * 4 + rr;
      const int grow = rowbase + wm * 32 + lr;
      if (grow >= N_NODES) continue;
      const uint4 v = *(const uint4*)(su + lr * 136 + c8);
      *(uint4*)((ushort_t*)OutV + (size_t)grow * Jdim + colbase + wn * 128 + c8) = v;
    }
  }
}

// ---------------------------------------------------------------- edge bucket
__global__ void hist_kernel(const int* __restrict__ idx0, int* __restrict__ counts)
{
  const int m = blockIdx.x * 256 + threadIdx.x;
  if (m < M_EDGES) atomicAdd(&counts[idx0[m]], 1);
}

__global__ __launch_bounds__(256) void scan1_kernel(const int* __restrict__ counts,
    int* __restrict__ offsets, int* __restrict__ bsums)
{
  __shared__ int tmp[256];
  const int t = threadIdx.x;
  const int i = blockIdx.x * 256 + t;
  const int v = (i < N_NODES) ? counts[i] : 0;
  int x = v;
  tmp[t] = x;
  __syncthreads();
#pragma unroll
  for (int off = 1; off < 256; off <<= 1) {
    const int a = (t >= off) ? tmp[t - off] : 0;
    __syncthreads();
    x += a;
    tmp[t] = x;
    __syncthreads();
  }
  if (i < N_NODES) offsets[i] = x - v;
  if (t == 255) bsums[blockIdx.x] = x;
}

__global__ __launch_bounds__(256) void scan2_kernel(int* __restrict__ bsums, int nb)
{
  __shared__ int tmp[256];
  const int t = threadIdx.x;
  const int v = (t < nb) ? bsums[t] : 0;
  int x = v;
  tmp[t] = x;
  __syncthreads();
#pragma unroll
  for (int off = 1; off < 256; off <<= 1) {
    const int a = (t >= off) ? tmp[t - off] : 0;
    __syncthreads();
    x += a;
    tmp[t] = x;
    __syncthreads();
  }
  if (t < nb) bsums[t] = x - v;
}

__global__ void scan3_kernel(int* __restrict__ offsets, const int* __restrict__ bsums)
{
  const int i = blockIdx.x * 256 + threadIdx.x;
  if (i < N_NODES) offsets[i] += bsums[blockIdx.x];
  if (i == 0) offsets[N_NODES] = M_EDGES;
}

__global__ void scatter_kernel(const int* __restrict__ idx0,
    const int* __restrict__ idx1, const int* __restrict__ offsets,
    int* __restrict__ cursor, int* __restrict__ srcs)
{
  const int m = blockIdx.x * 256 + threadIdx.x;
  if (m < M_EDGES) {
    const int n = idx0[m];
    const int p = offsets[n] + atomicAdd(&cursor[n], 1);
    srcs[p] = idx1[m];
  }
}

// ---------------------------------------------------------------- attention
// One node per wave. 32 lanes cooperatively hold one edge's K/V row:
// lane l<32 owns 8 dims (uint4) of head l>>2. Wave halves process alternating
// edges with independent online softmax, merged at the end via shfl_xor(32).
// Per load inst: 2 edges x 8 contiguous lines = 16 lines (vs 64 in round 6).
__global__ __launch_bounds__(256) void attn_kernel(
    const ushort_t* __restrict__ QKVh, const int* __restrict__ offsets,
    const int* __restrict__ srcs, ushort_t* __restrict__ AO)
{
  const int node = blockIdx.x * 4 + (threadIdx.x >> 6);
  if (node >= N_NODES) return;
  const int lane = threadIdx.x & 63;
  const int l32 = lane & 31;
  const int half = lane >> 5;
  const int start = offsets[node];
  const int end = offsets[node + 1];

  // Q fragment: 8 bf16 dims of head l32>>2 (Q pre-scaled by ATT_SCALE in GEMM)
  const uint4 qp = *(const uint4*)((const uint_t*)(QKVh + (size_t)node * 768) + l32 * 4);

  float m = NEG_BIG, s = 0.f;
  float o[8];
#pragma unroll
  for (int j = 0; j < 8; ++j) o[j] = 0.f;

  for (int e = start + half; e < end; e += 4) {
    const int eB = e + 2;
    const bool hasB = eB < end;
    const int sA = srcs[e];
    const int sB = srcs[hasB ? eB : e];
    const uint_t* rA = (const uint_t*)(QKVh + (size_t)sA * 768);
    const uint_t* rB = (const uint_t*)(QKVh + (size_t)sB * 768);
    const uint4 kA = *(const uint4*)(rA + 128 + l32 * 4);
    const uint4 kB = *(const uint4*)(rB + 128 + l32 * 4);
    const uint4 vA = *(const uint4*)(rA + 256 + l32 * 4);
    const uint4 vB = *(const uint4*)(rB + 256 + l32 * 4);

    float dA = bf_even(qp.x) * bf_even(kA.x) + bf_odd(qp.x) * bf_odd(kA.x)
             + bf_even(qp.y) * bf_even(kA.y) + bf_odd(qp.y) * bf_odd(kA.y)
             + bf_even(qp.z) * bf_even(kA.z) + bf_odd(qp.z) * bf_odd(kA.z)
             + bf_even(qp.w) * bf_even(kA.w) + bf_odd(qp.w) * bf_odd(kA.w);
    dA += __shfl_xor(dA, 1);
    dA += __shfl_xor(dA, 2);
    float dB = bf_even(qp.x) * bf_even(kB.x) + bf_odd(qp.x) * bf_odd(kB.x)
             + bf_even(qp.y) * bf_even(kB.y) + bf_odd(qp.y) * bf_odd(kB.y)
             + bf_even(qp.z) * bf_even(kB.z) + bf_odd(qp.z) * bf_odd(kB.z)
             + bf_even(qp.w) * bf_even(kB.w) + bf_odd(qp.w) * bf_odd(kB.w);
    dB += __shfl_xor(dB, 1);
    dB += __shfl_xor(dB, 2);

    const float lA = dA * LOG2E;
    const float lB = hasB ? dB * LOG2E : NEG_BIG;
    const float mn = fmaxf(m, fmaxf(lA, lB));
    const float fac = exp2f(m - mn);
    const float wA = exp2f(lA - mn);
    const float wB = hasB ? exp2f(lB - mn) : 0.f;
    m = mn;
    s = s * fac + wA + wB;
    o[0] = o[0] * fac + wA * bf_even(vA.x) + wB * bf_even(vB.x);
    o[1] = o[1] * fac + wA * bf_odd(vA.x)  + wB * bf_odd(vB.x);
    o[2] = o[2] * fac + wA * bf_even(vA.y) + wB * bf_even(vB.y);
    o[3] = o[3] * fac + wA * bf_odd(vA.y)  + wB * bf_odd(vB.y);
    o[4] = o[4] * fac + wA * bf_even(vA.z) + wB * bf_even(vB.z);
    o[5] = o[5] * fac + wA * bf_odd(vA.z)  + wB * bf_odd(vB.z);
    o[6] = o[6] * fac + wA * bf_even(vA.w) + wB * bf_even(vB.w);
    o[7] = o[7] * fac + wA * bf_odd(vA.w)  + wB * bf_odd(vB.w);
  }

  // merge the two halves' online softmax states
  const float mO = __shfl_xor(m, 32);
  const float sO = __shfl_xor(s, 32);
  const float mm = fmaxf(m, mO);
  const float fS = exp2f(m - mm);
  const float fO = exp2f(mO - mm);
  const float st = s * fS + sO * fO;
  float out[8];
#pragma unroll
  for (int j = 0; j < 8; ++j) out[j] = o[j] * fS + __shfl_xor(o[j], 32) * fO;

  const float inv = (end > start) ? 1.0f / st : 0.0f;
  if (lane < 32) {
    uint4 st4;
    st4.x = (uint_t)f2bf(out[0] * inv) | ((uint_t)f2bf(out[1] * inv) << 16);
    st4.y = (uint_t)f2bf(out[2] * inv) | ((uint_t)f2bf(out[3] * inv) << 16);
    st4.z = (uint_t)f2bf(out[4] * inv) | ((uint_t)f2bf(out[5] * inv) << 16);
    st4.w = (uint_t)f2bf(out[6] * inv) | ((uint_t)f2bf(out[7] * inv) << 16);
    *(uint4*)((uint_t*)(AO + (size_t)node * 256) + l32 * 4) = st4;
  }
}

// ---------------------------------------------------------------- launch
extern "C" void kernel_launch(void* const* d_in, const int* in_sizes, int n_in,
                              void* d_out, int out_size, void* d_ws,
                              size_t ws_size, hipStream_t stream)
{
  const float* feats  = (const float*)d_in[0];
  const int*   edge   = (const int*)d_in[2];
  const float* ln1_g  = (const float*)d_in[3];
  const float* ln1_b  = (const float*)d_in[4];
  const float* qkv_w  = (const float*)d_in[5];
  const float* qkv_b  = (const float*)d_in[6];
  const float* proj_w = (const float*)d_in[7];
  const float* proj_b = (const float*)d_in[8];
  const float* ln2_g  = (const float*)d_in[9];
  const float* ln2_b  = (const float*)d_in[10];
  const float* fc1_w  = (const float*)d_in[11];
  const float* fc1_b  = (const float*)d_in[12];
  const float* fc2_w  = (const float*)d_in[13];
  const float* fc2_b  = (const float*)d_in[14];
  float* out = (float*)d_out;

  ushort_t* Xb   = (ushort_t*)d_ws;                       // N*256 bf16
  ushort_t* QKVh = Xb + (size_t)N_NODES * 256;            // N*768 bf16
  ushort_t* AOb  = QKVh + (size_t)N_NODES * 768;          // N*256 bf16
  ushort_t* Hb   = QKVh;                                  // N*1024 overlay
  ushort_t* wb   = AOb + (size_t)N_NODES * 256;           // 786432 bf16
  ushort_t* qkv_wb  = wb;
  ushort_t* proj_wb = qkv_wb + 768 * 256;
  ushort_t* fc1_wb  = proj_wb + 256 * 256;
  ushort_t* fc2_wb  = fc1_wb + 1024 * 256;
  int* counts  = (int*)(fc2_wb + 256 * 1024);
  int* cursor  = counts + N_NODES;
  int* offsets = cursor + N_NODES;
  int* srcs    = offsets + N_NODES + 1;
  int* bsums   = srcs + M_EDGES;
  const size_t required = (size_t)((char*)(bsums + 256) - (char*)d_ws);
  if (ws_size < required) {
    hipMemsetAsync(d_out, 0, (size_t)out_size * sizeof(float), stream);
    return;
  }
  const int* idx0 = edge;
  const int* idx1 = edge + M_EDGES;
  const int rowTiles = (N_NODES + 63) / 64;      // 782
  const int scanBlocks = (N_NODES + 255) / 256;  // 196

  hipMemsetAsync(counts, 0, 2 * N_NODES * sizeof(int), stream);
  cvt_kernel<<<786432 / 256, 256, 0, stream>>>(qkv_w, proj_w, fc1_w, fc2_w, wb);

  ln_kernel<<<N_NODES / 4, 256, 0, stream>>>(feats, ln1_g, ln1_b, Xb);
  mfma_gemm<0><<<dim3(768 / 256, rowTiles), 256, 0, stream>>>(
      Xb, qkv_wb, qkv_b, nullptr, QKVh, 256, 768);
  hist_kernel<<<(M_EDGES + 255) / 256, 256, 0, stream>>>(idx0, counts);
  scan1_kernel<<<scanBlocks, 256, 0, stream>>>(counts, offsets, bsums);
  scan2_kernel<<<1, 256, 0, stream>>>(bsums, scanBlocks);
  scan3_kernel<<<scanBlocks, 256, 0, stream>>>(offsets, bsums);
  scatter_kernel<<<(M_EDGES + 255) / 256, 256, 0, stream>>>(idx0, idx1, offsets,
                                                            cursor, srcs);
  attn_kernel<<<N_NODES / 4, 256, 0, stream>>>(QKVh, offsets, srcs, AOb);
  mfma_gemm<1><<<dim3(256 / 256, rowTiles), 256, 0, stream>>>(
      AOb, proj_wb, proj_b, feats, out, 256, 256);
  ln_kernel<<<N_NODES / 4, 256, 0, stream>>>(out, ln2_g, ln2_b, Xb);
  mfma_gemm<2><<<dim3(1024 / 256, rowTiles), 256, 0, stream>>>(
      Xb, fc1_wb, fc1_b, nullptr, Hb, 256, 1024);
  mfma_gemm<1><<<dim3(256 / 256, rowTiles), 256, 0, stream>>>(
      Hb, fc2_wb, fc2_b, out, out, 1024, 256);
}

// Round 4
// 538.925 us; speedup vs baseline: 1.0452x; 1.0292x over previous
//
#include <hip/hip_runtime.h>
#include <hip/hip_bf16.h>
#include <cmath>

// TransformerBlock: N=50000, C=256, H=8, HD=32, M=800000 edges, HID=1024.
// Round 9:
//  * mfma_gemm: double-buffered 2-phase K-loop (T3-minimum). Old structure
//    was stage -> sync(vmcnt0 drain) -> compute -> sync: every K-step pays
//    full HBM latency serially (GEMM family inferred ~380us vs ~120us
//    roofline). New: prologue-stage buf0; per iter {STAGE(buf^1,t+1);
//    compute(buf); __syncthreads()} -- next-tile loads drain during compute,
//    one barrier per K-step. LDS 2x40KB=80KB -> 2 blocks/CU.
//  * launch_bounds back to (256,2) ((256,3) suspected VGPR squeeze, round-3
//    non-attn time regressed ~8us).
//  * attn unchanged (round-3 analysis: FETCH 386MB == 8 XCD x 48MB = every
//    XCD streams K/V once; at scatter-achievable ~3.5TB/s that's ~110us ->
//    attn is at its structural floor for bf16 K/V).
// ws: Xb 25.6MB | QKVh 76.8MB | AOb 25.6MB (QKVh+AOb reused as H 102.4MB)
//     | wb 1.6MB | int meta ~3.8MB => ~133.5MB.

#define N_NODES 50000
#define C_DIM 256
#define M_EDGES 800000
#define ATT_SCALE 0.17677669529663687f /* 32^-0.5 */
#define LN_EPS 1e-5f
#define LOG2E 1.4426950408889634f
#define NEG_BIG -3.0e38f

typedef unsigned int uint_t;
typedef unsigned short ushort_t;
typedef short short8 __attribute__((ext_vector_type(8)));
typedef float floatx4 __attribute__((ext_vector_type(4)));

__device__ __forceinline__ ushort_t f2bf(float f) {
  uint_t u = __float_as_uint(f);
  return (ushort_t)((u + 0x7FFFu + ((u >> 16) & 1u)) >> 16);  // RNE
}
__device__ __forceinline__ float bf_even(uint_t u) { return __uint_as_float(u << 16); }
__device__ __forceinline__ float bf_odd(uint_t u) { return __uint_as_float(u & 0xFFFF0000u); }

__device__ __forceinline__ float gelu_tanh(float x) {
  // tanh-form gelu; |diff vs exact erf gelu| <= ~3e-3, within error budget
  const float u = 0.7978845608028654f * (x + 0.044715f * x * x * x);
  const float e = __expf(2.0f * u);
  const float t = 1.0f - 2.0f / (e + 1.0f);
  return 0.5f * x * (1.0f + t);
}

__device__ __forceinline__ void gload16(const void* g, void* l) {
  __builtin_amdgcn_global_load_lds(
      (const __attribute__((address_space(1))) void*)g,
      (__attribute__((address_space(3))) void*)l, 16, 0, 0);
}

// ---------------------------------------------------------------- LayerNorm
// One row per wave: 64 lanes x float4 = 256 floats. No LDS, no barriers.
__global__ __launch_bounds__(256) void ln_kernel(const float* __restrict__ x,
    const float* __restrict__ g, const float* __restrict__ b,
    ushort_t* __restrict__ y)
{
  const int row = blockIdx.x * 4 + (threadIdx.x >> 6);
  const int lane = threadIdx.x & 63;
  const float4 v = *(const float4*)(x + (size_t)row * C_DIM + lane * 4);
  float s = v.x + v.y + v.z + v.w;
  float s2 = v.x * v.x + v.y * v.y + v.z * v.z + v.w * v.w;
#pragma unroll
  for (int m = 1; m < 64; m <<= 1) {
    s += __shfl_xor(s, m);
    s2 += __shfl_xor(s2, m);
  }
  const float mean = s * (1.0f / 256.0f);
  const float var = fmaxf(s2 * (1.0f / 256.0f) - mean * mean, 0.0f);
  const float r = rsqrtf(var + LN_EPS);
  const float4 g4 = *(const float4*)(g + lane * 4);
  const float4 b4 = *(const float4*)(b + lane * 4);
  ushort4 o;
  o.x = f2bf((v.x - mean) * r * g4.x + b4.x);
  o.y = f2bf((v.y - mean) * r * g4.y + b4.y);
  o.z = f2bf((v.z - mean) * r * g4.z + b4.z);
  o.w = f2bf((v.w - mean) * r * g4.w + b4.w);
  *(ushort4*)(y + (size_t)row * C_DIM + lane * 4) = o;
}

// ------------------------------------------------- fused fp32->bf16 weights
__global__ void cvt_kernel(const float* __restrict__ s0, const float* __restrict__ s1,
                           const float* __restrict__ s2, const float* __restrict__ s3,
                           ushort_t* __restrict__ dst)
{
  const int i = blockIdx.x * 256 + threadIdx.x;
  // segments: qkv_w 196608 | proj_w 65536 | fc1_w 262144 | fc2_w 262144
  float v;
  if (i < 196608) v = s0[i];
  else if (i < 262144) v = s1[i - 196608];
  else if (i < 524288) v = s2[i - 262144];
  else v = s3[i - 524288];
  dst[i] = f2bf(v);
}

// ---------------------------------------------------------------- MFMA GEMM
// Out[n][j] = sum_k A[n][k]*W[j][k] + bias[j] (+ epilogue). BK=64.
// EPI 0: cols<256 *= ATT_SCALE; bf16 out (qkv)
// EPI 1: + extra[n][j]; fp32 out (proj+skip, fc2+skip)
// EPI 2: tanh-gelu; bf16 out (fc1)
// 64x256 tile, 4 waves -> 32x128 quadrants, 2x8 16x16x32 MFMAs x 2 k-halves.
// Double-buffered 2-phase K-loop: STAGE(next) issued before compute(cur),
// one __syncthreads per K-step (vmcnt+lgkm drain covers both hazards:
// next-buf writes vs prev reads, and cur-buf readiness).
// K-loop LDS: A 64x64 + B 256x64 bf16 row-major, chunk (r,kc) at kc^(r&7).
// Epilogue: per-wave LDS transpose (8.5KB/wave) -> float4/ushort8 stores.
template <int EPI>
__global__ __launch_bounds__(256, 2) void mfma_gemm(
    const ushort_t* __restrict__ A, const ushort_t* __restrict__ W,
    const float* __restrict__ bias, const float* __restrict__ extra,
    void* __restrict__ OutV, int Kdim, int Jdim)
{
  __shared__ __align__(16) char smem[81920];  // 2 x (A 8KB + B 32KB)
  const int t = threadIdx.x;
  const int lane = t & 63;
  const int w = t >> 6;
  const int wm = w & 1;    // row half (32 rows)
  const int wn = w >> 1;   // col half (128 cols)
  const int rowbase = blockIdx.y * 64;
  const int colbase = blockIdx.x * 256;

  floatx4 acc[2][8] = {};

  // staging geometry: linear chunk cidx = h*256 + base; row = h*32 + rbase.
  const int base = w * 64 + lane;            // 0..255
  const int rbase = base >> 3;               // 0..31
  const int kcs = (base & 7) ^ (rbase & 7);  // same for all h (h*32 % 8 == 0)

  const int rl = lane & 15;
  const int qd = lane >> 4;  // 0..3

  int growA[2];
#pragma unroll
  for (int h = 0; h < 2; ++h) {
    int grow = rowbase + h * 32 + rbase;
    if (grow > N_NODES - 1) grow = N_NODES - 1;  // clamp tail rows
    growA[h] = grow;
  }

  const int nk = Kdim >> 6;

  {  // prologue: stage K-tile 0 into buf 0
    ushort_t* Ab = (ushort_t*)smem;
    ushort_t* Bb = Ab + 4096;
#pragma unroll
    for (int h = 0; h < 2; ++h)
      gload16(A + (size_t)growA[h] * Kdim + kcs * 8, Ab + (h * 256 + w * 64) * 8);
#pragma unroll
    for (int h = 0; h < 8; ++h) {
      const int gcol = colbase + h * 32 + rbase;   // Jdim multiple of 256
      gload16(W + (size_t)gcol * Kdim + kcs * 8, Bb + (h * 256 + w * 64) * 8);
    }
  }
  __syncthreads();

  for (int kt = 0; kt < nk; ++kt) {
    const int cur = kt & 1;
    if (kt + 1 < nk) {  // stage next K-tile into the other buffer
      const int k0n = (kt + 1) << 6;
      ushort_t* Ab = (ushort_t*)smem + (cur ^ 1) * 20480;
      ushort_t* Bb = Ab + 4096;
#pragma unroll
      for (int h = 0; h < 2; ++h)
        gload16(A + (size_t)growA[h] * Kdim + k0n + kcs * 8,
                Ab + (h * 256 + w * 64) * 8);
#pragma unroll
      for (int h = 0; h < 8; ++h) {
        const int gcol = colbase + h * 32 + rbase;
        gload16(W + (size_t)gcol * Kdim + k0n + kcs * 8,
                Bb + (h * 256 + w * 64) * 8);
      }
    }

    const ushort_t* As = (const ushort_t*)smem + cur * 20480;
    const ushort_t* Bs = As + 4096;
#pragma unroll
    for (int h = 0; h < 2; ++h) {
      short8 af[2], bfr[8];
#pragma unroll
      for (int tm = 0; tm < 2; ++tm) {
        const int ra = wm * 32 + tm * 16 + rl;
        const int kc = (h * 4 + qd) ^ (ra & 7);
        af[tm] = *(const short8*)(As + ra * 64 + kc * 8);
      }
#pragma unroll
      for (int tn = 0; tn < 8; ++tn) {
        const int rb = wn * 128 + tn * 16 + rl;
        const int kc = (h * 4 + qd) ^ (rb & 7);
        bfr[tn] = *(const short8*)(Bs + rb * 64 + kc * 8);
      }
#pragma unroll
      for (int tm = 0; tm < 2; ++tm)
#pragma unroll
        for (int tn = 0; tn < 8; ++tn)
          acc[tm][tn] = __builtin_amdgcn_mfma_f32_16x16x32_bf16(
              af[tm], bfr[tn], acc[tm][tn], 0, 0, 0);
    }
    __syncthreads();
  }

  // ---- epilogue: LDS transpose -> full-line vector stores ----
  const int rr = lane >> 4;        // 0..3 (row group in read phase)
  if (EPI == 1) {
    float* sc = (float*)smem + w * (32 * 68);  // 32 rows x stride 68 fp32
    const int c4 = (lane & 15) * 4;            // 0..60
#pragma unroll
    for (int p = 0; p < 2; ++p) {
      __syncthreads();
#pragma unroll
      for (int th = 0; th < 4; ++th) {
        const int tn = p * 4 + th;
#pragma unroll
        for (int tm = 0; tm < 2; ++tm)
#pragma unroll
          for (int r = 0; r < 4; ++r)
            sc[(tm * 16 + qd * 4 + r) * 68 + th * 16 + rl] = acc[tm][tn][r];
      }
      __syncthreads();
      const int col0 = colbase + wn * 128 + p * 64 + c4;
      const float4 b4 = *(const float4*)(bias + col0);
#pragma unroll
      for (int it = 0; it < 8; ++it) {
        const int lr = it * 4 + rr;
        const int grow = rowbase + wm * 32 + lr;
        if (grow >= N_NODES) continue;
        float4 v = *(const float4*)(sc + lr * 68 + c4);
        const float4 e4 = *(const float4*)(extra + (size_t)grow * Jdim + col0);
        v.x += b4.x + e4.x; v.y += b4.y + e4.y;
        v.z += b4.z + e4.z; v.w += b4.w + e4.w;
        *(float4*)((float*)OutV + (size_t)grow * Jdim + col0) = v;
      }
    }
  } else {
    __syncthreads();
    ushort_t* su = (ushort_t*)smem + w * (32 * 136);  // 32 rows x stride 136
#pragma unroll
    for (int tn = 0; tn < 8; ++tn) {
      const int col = colbase + wn * 128 + tn * 16 + rl;
      const float bv = bias[col];
#pragma unroll
      for (int tm = 0; tm < 2; ++tm)
#pragma unroll
        for (int r = 0; r < 4; ++r) {
          float v = acc[tm][tn][r] + bv;
          if (EPI == 0) {
            if (col < 256) v *= ATT_SCALE;
          } else {
            v = gelu_tanh(v);
          }
          su[(tm * 16 + qd * 4 + r) * 136 + tn * 16 + rl] = f2bf(v);
        }
    }
    __syncthreads();
    const int c8 = (lane & 15) * 8;
#pragma unroll
    for (int it = 0; it < 8; ++it) {
      const int lr = it * 4 + rr;
      const int grow = rowbase + wm * 32 + lr;
      if (grow >= N_NODES) continue;
      const uint4 v = *(const uint4*)(su + lr * 136 + c8);
      *(uint4*)((ushort_t*)OutV + (size_t)grow * Jdim + colbase + wn * 128 + c8) = v;
    }
  }
}

// ---------------------------------------------------------------- edge bucket
__global__ void hist_kernel(const int* __restrict__ idx0, int* __restrict__ counts)
{
  const int m = blockIdx.x * 256 + threadIdx.x;
  if (m < M_EDGES) atomicAdd(&counts[idx0[m]], 1);
}

__global__ __launch_bounds__(256) void scan1_kernel(const int* __restrict__ counts,
    int* __restrict__ offsets, int* __restrict__ bsums)
{
  __shared__ int tmp[256];
  const int t = threadIdx.x;
  const int i = blockIdx.x * 256 + t;
  const int v = (i < N_NODES) ? counts[i] : 0;
  int x = v;
  tmp[t] = x;
  __syncthreads();
#pragma unroll
  for (int off = 1; off < 256; off <<= 1) {
    const int a = (t >= off) ? tmp[t - off] : 0;
    __syncthreads();
    x += a;
    tmp[t] = x;
    __syncthreads();
  }
  if (i < N_NODES) offsets[i] = x - v;
  if (t == 255) bsums[blockIdx.x] = x;
}

__global__ __launch_bounds__(256) void scan2_kernel(int* __restrict__ bsums, int nb)
{
  __shared__ int tmp[256];
  const int t = threadIdx.x;
  const int v = (t < nb) ? bsums[t] : 0;
  int x = v;
  tmp[t] = x;
  __syncthreads();
#pragma unroll
  for (int off = 1; off < 256; off <<= 1) {
    const int a = (t >= off) ? tmp[t - off] : 0;
    __syncthreads();
    x += a;
    tmp[t] = x;
    __syncthreads();
  }
  if (t < nb) bsums[t] = x - v;
}

__global__ void scan3_kernel(int* __restrict__ offsets, const int* __restrict__ bsums)
{
  const int i = blockIdx.x * 256 + threadIdx.x;
  if (i < N_NODES) offsets[i] += bsums[blockIdx.x];
  if (i == 0) offsets[N_NODES] = M_EDGES;
}

__global__ void scatter_kernel(const int* __restrict__ idx0,
    const int* __restrict__ idx1, const int* __restrict__ offsets,
    int* __restrict__ cursor, int* __restrict__ srcs)
{
  const int m = blockIdx.x * 256 + threadIdx.x;
  if (m < M_EDGES) {
    const int n = idx0[m];
    const int p = offsets[n] + atomicAdd(&cursor[n], 1);
    srcs[p] = idx1[m];
  }
}

// ---------------------------------------------------------------- attention
// One node per wave. 32 lanes cooperatively hold one edge's K/V row:
// lane l<32 owns 8 dims (uint4) of head l>>2. Wave halves process alternating
// edges with independent online softmax, merged at the end via shfl_xor(32).
__global__ __launch_bounds__(256) void attn_kernel(
    const ushort_t* __restrict__ QKVh, const int* __restrict__ offsets,
    const int* __restrict__ srcs, ushort_t* __restrict__ AO)
{
  const int node = blockIdx.x * 4 + (threadIdx.x >> 6);
  if (node >= N_NODES) return;
  const int lane = threadIdx.x & 63;
  const int l32 = lane & 31;
  const int half = lane >> 5;
  const int start = offsets[node];
  const int end = offsets[node + 1];

  // Q fragment: 8 bf16 dims of head l32>>2 (Q pre-scaled by ATT_SCALE in GEMM)
  const uint4 qp = *(const uint4*)((const uint_t*)(QKVh + (size_t)node * 768) + l32 * 4);

  float m = NEG_BIG, s = 0.f;
  float o[8];
#pragma unroll
  for (int j = 0; j < 8; ++j) o[j] = 0.f;

  for (int e = start + half; e < end; e += 4) {
    const int eB = e + 2;
    const bool hasB = eB < end;
    const int sA = srcs[e];
    const int sB = srcs[hasB ? eB : e];
    const uint_t* rA = (const uint_t*)(QKVh + (size_t)sA * 768);
    const uint_t* rB = (const uint_t*)(QKVh + (size_t)sB * 768);
    const uint4 kA = *(const uint4*)(rA + 128 + l32 * 4);
    const uint4 kB = *(const uint4*)(rB + 128 + l32 * 4);
    const uint4 vA = *(const uint4*)(rA + 256 + l32 * 4);
    const uint4 vB = *(const uint4*)(rB + 256 + l32 * 4);

    float dA = bf_even(qp.x) * bf_even(kA.x) + bf_odd(qp.x) * bf_odd(kA.x)
             + bf_even(qp.y) * bf_even(kA.y) + bf_odd(qp.y) * bf_odd(kA.y)
             + bf_even(qp.z) * bf_even(kA.z) + bf_odd(qp.z) * bf_odd(kA.z)
             + bf_even(qp.w) * bf_even(kA.w) + bf_odd(qp.w) * bf_odd(kA.w);
    dA += __shfl_xor(dA, 1);
    dA += __shfl_xor(dA, 2);
    float dB = bf_even(qp.x) * bf_even(kB.x) + bf_odd(qp.x) * bf_odd(kB.x)
             + bf_even(qp.y) * bf_even(kB.y) + bf_odd(qp.y) * bf_odd(kB.y)
             + bf_even(qp.z) * bf_even(kB.z) + bf_odd(qp.z) * bf_odd(kB.z)
             + bf_even(qp.w) * bf_even(kB.w) + bf_odd(qp.w) * bf_odd(kB.w);
    dB += __shfl_xor(dB, 1);
    dB += __shfl_xor(dB, 2);

    const float lA = dA * LOG2E;
    const float lB = hasB ? dB * LOG2E : NEG_BIG;
    const float mn = fmaxf(m, fmaxf(lA, lB));
    const float fac = exp2f(m - mn);
    const float wA = exp2f(lA - mn);
    const float wB = hasB ? exp2f(lB - mn) : 0.f;
    m = mn;
    s = s * fac + wA + wB;
    o[0] = o[0] * fac + wA * bf_even(vA.x) + wB * bf_even(vB.x);
    o[1] = o[1] * fac + wA * bf_odd(vA.x)  + wB * bf_odd(vB.x);
    o[2] = o[2] * fac + wA * bf_even(vA.y) + wB * bf_even(vB.y);
    o[3] = o[3] * fac + wA * bf_odd(vA.y)  + wB * bf_odd(vB.y);
    o[4] = o[4] * fac + wA * bf_even(vA.z) + wB * bf_even(vB.z);
    o[5] = o[5] * fac + wA * bf_odd(vA.z)  + wB * bf_odd(vB.z);
    o[6] = o[6] * fac + wA * bf_even(vA.w) + wB * bf_even(vB.w);
    o[7] = o[7] * fac + wA * bf_odd(vA.w)  + wB * bf_odd(vB.w);
  }

  // merge the two halves' online softmax states
  const float mO = __shfl_xor(m, 32);
  const float sO = __shfl_xor(s, 32);
  const float mm = fmaxf(m, mO);
  const float fS = exp2f(m - mm);
  const float fO = exp2f(mO - mm);
  const float st = s * fS + sO * fO;
  float out[8];
#pragma unroll
  for (int j = 0; j < 8; ++j) out[j] = o[j] * fS + __shfl_xor(o[j], 32) * fO;

  const float inv = (end > start) ? 1.0f / st : 0.0f;
  if (lane < 32) {
    uint4 st4;
    st4.x = (uint_t)f2bf(out[0] * inv) | ((uint_t)f2bf(out[1] * inv) << 16);
    st4.y = (uint_t)f2bf(out[2] * inv) | ((uint_t)f2bf(out[3] * inv) << 16);
    st4.z = (uint_t)f2bf(out[4] * inv) | ((uint_t)f2bf(out[5] * inv) << 16);
    st4.w = (uint_t)f2bf(out[6] * inv) | ((uint_t)f2bf(out[7] * inv) << 16);
    *(uint4*)((uint_t*)(AO + (size_t)node * 256) + l32 * 4) = st4;
  }
}

// ---------------------------------------------------------------- launch
extern "C" void kernel_launch(void* const* d_in, const int* in_sizes, int n_in,
                              void* d_out, int out_size, void* d_ws,
                              size_t ws_size, hipStream_t stream)
{
  const float* feats  = (const float*)d_in[0];
  const int*   edge   = (const int*)d_in[2];
  const float* ln1_g  = (const float*)d_in[3];
  const float* ln1_b  = (const float*)d_in[4];
  const float* qkv_w  = (const float*)d_in[5];
  const float* qkv_b  = (const float*)d_in[6];
  const float* proj_w = (const float*)d_in[7];
  const float* proj_b = (const float*)d_in[8];
  const float* ln2_g  = (const float*)d_in[9];
  const float* ln2_b  = (const float*)d_in[10];
  const float* fc1_w  = (const float*)d_in[11];
  const float* fc1_b  = (const float*)d_in[12];
  const float* fc2_w  = (const float*)d_in[13];
  const float* fc2_b  = (const float*)d_in[14];
  float* out = (float*)d_out;

  ushort_t* Xb   = (ushort_t*)d_ws;                       // N*256 bf16
  ushort_t* QKVh = Xb + (size_t)N_NODES * 256;            // N*768 bf16
  ushort_t* AOb  = QKVh + (size_t)N_NODES * 768;          // N*256 bf16
  ushort_t* Hb   = QKVh;                                  // N*1024 overlay
  ushort_t* wb   = AOb + (size_t)N_NODES * 256;           // 786432 bf16
  ushort_t* qkv_wb  = wb;
  ushort_t* proj_wb = qkv_wb + 768 * 256;
  ushort_t* fc1_wb  = proj_wb + 256 * 256;
  ushort_t* fc2_wb  = fc1_wb + 1024 * 256;
  int* counts  = (int*)(fc2_wb + 256 * 1024);
  int* cursor  = counts + N_NODES;
  int* offsets = cursor + N_NODES;
  int* srcs    = offsets + N_NODES + 1;
  int* bsums   = srcs + M_EDGES;
  const size_t required = (size_t)((char*)(bsums + 256) - (char*)d_ws);
  if (ws_size < required) {
    hipMemsetAsync(d_out, 0, (size_t)out_size * sizeof(float), stream);
    return;
  }
  const int* idx0 = edge;
  const int* idx1 = edge + M_EDGES;
  const int rowTiles = (N_NODES + 63) / 64;      // 782
  const int scanBlocks = (N_NODES + 255) / 256;  // 196

  hipMemsetAsync(counts, 0, 2 * N_NODES * sizeof(int), stream);
  cvt_kernel<<<786432 / 256, 256, 0, stream>>>(qkv_w, proj_w, fc1_w, fc2_w, wb);

  ln_kernel<<<N_NODES / 4, 256, 0, stream>>>(feats, ln1_g, ln1_b, Xb);
  mfma_gemm<0><<<dim3(768 / 256, rowTiles), 256, 0, stream>>>(
      Xb, qkv_wb, qkv_b, nullptr, QKVh, 256, 768);
  hist_kernel<<<(M_EDGES + 255) / 256, 256, 0, stream>>>(idx0, counts);
  scan1_kernel<<<scanBlocks, 256, 0, stream>>>(counts, offsets, bsums);
  scan2_kernel<<<1, 256, 0, stream>>>(bsums, scanBlocks);
  scan3_kernel<<<scanBlocks, 256, 0, stream>>>(offsets, bsums);
  scatter_kernel<<<(M_EDGES + 255) / 256, 256, 0, stream>>>(idx0, idx1, offsets,
                                                            cursor, srcs);
  attn_kernel<<<N_NODES / 4, 256, 0, stream>>>(QKVh, offsets, srcs, AOb);
  mfma_gemm<1><<<dim3(256 / 256, rowTiles), 256, 0, stream>>>(
      AOb, proj_wb, proj_b, feats, out, 256, 256);
  ln_kernel<<<N_NODES / 4, 256, 0, stream>>>(out, ln2_g, ln2_b, Xb);
  mfma_gemm<2><<<dim3(1024 / 256, rowTiles), 256, 0, stream>>>(
      Xb, fc1_wb, fc1_b, nullptr, Hb, 256, 1024);
  mfma_gemm<1><<<dim3(256 / 256, rowTiles), 256, 0, stream>>>(
      Hb, fc2_wb, fc2_b, out, out, 1024, 256);
}

// Round 6
// 525.611 us; speedup vs baseline: 1.0716x; 1.0253x over previous
//
#include <hip/hip_runtime.h>
#include <hip/hip_bf16.h>
#include <cmath>

// TransformerBlock: N=50000, C=256, H=8, HD=32, M=800000 edges, HID=1024.
// Round 11: BUGFIX of round 10 (one line). Read-side LDS swizzle used
// (rl>>2)&3; write side swizzles by row&3 = rl&3. Rows with rl&3 !=
// (rl>>2)&3 read permuted K-chunks -> absmax 5.23. Fixed:
// soff = (qd ^ (rl&3)) * 8. Everything else identical to round 10:
//  * mfma_gemm: BK=32, dbuf LDS 40KB -> 4 blocks/CU (16 waves/CU),
//    __launch_bounds__(256,4). TLP hides the per-K-step vmcnt drain
//    (round-9: 1-deep prefetch at 2 blocks/CU gained only 16us because
//    compute < HBM latency and no other waves to run during the drain).
//  * attn unchanged (structural floor: FETCH 386MB == 8 XCD x ~48MB, every
//    XCD streams K/V once; ~3.6TB/s achieved).
// ws: Xb 25.6MB | QKVh 76.8MB | AOb 25.6MB (QKVh+AOb reused as H 102.4MB)
//     | wb 1.6MB | int meta ~3.8MB => ~133.5MB.

#define N_NODES 50000
#define C_DIM 256
#define M_EDGES 800000
#define ATT_SCALE 0.17677669529663687f /* 32^-0.5 */
#define LN_EPS 1e-5f
#define LOG2E 1.4426950408889634f
#define NEG_BIG -3.0e38f

typedef unsigned int uint_t;
typedef unsigned short ushort_t;
typedef short short8 __attribute__((ext_vector_type(8)));
typedef float floatx4 __attribute__((ext_vector_type(4)));

__device__ __forceinline__ ushort_t f2bf(float f) {
  uint_t u = __float_as_uint(f);
  return (ushort_t)((u + 0x7FFFu + ((u >> 16) & 1u)) >> 16);  // RNE
}
__device__ __forceinline__ float bf_even(uint_t u) { return __uint_as_float(u << 16); }
__device__ __forceinline__ float bf_odd(uint_t u) { return __uint_as_float(u & 0xFFFF0000u); }

__device__ __forceinline__ float gelu_tanh(float x) {
  // tanh-form gelu; |diff vs exact erf gelu| <= ~3e-3, within error budget
  const float u = 0.7978845608028654f * (x + 0.044715f * x * x * x);
  const float e = __expf(2.0f * u);
  const float t = 1.0f - 2.0f / (e + 1.0f);
  return 0.5f * x * (1.0f + t);
}

__device__ __forceinline__ void gload16(const void* g, void* l) {
  __builtin_amdgcn_global_load_lds(
      (const __attribute__((address_space(1))) void*)g,
      (__attribute__((address_space(3))) void*)l, 16, 0, 0);
}

// ---------------------------------------------------------------- LayerNorm
// One row per wave: 64 lanes x float4 = 256 floats. No LDS, no barriers.
__global__ __launch_bounds__(256) void ln_kernel(const float* __restrict__ x,
    const float* __restrict__ g, const float* __restrict__ b,
    ushort_t* __restrict__ y)
{
  const int row = blockIdx.x * 4 + (threadIdx.x >> 6);
  const int lane = threadIdx.x & 63;
  const float4 v = *(const float4*)(x + (size_t)row * C_DIM + lane * 4);
  float s = v.x + v.y + v.z + v.w;
  float s2 = v.x * v.x + v.y * v.y + v.z * v.z + v.w * v.w;
#pragma unroll
  for (int m = 1; m < 64; m <<= 1) {
    s += __shfl_xor(s, m);
    s2 += __shfl_xor(s2, m);
  }
  const float mean = s * (1.0f / 256.0f);
  const float var = fmaxf(s2 * (1.0f / 256.0f) - mean * mean, 0.0f);
  const float r = rsqrtf(var + LN_EPS);
  const float4 g4 = *(const float4*)(g + lane * 4);
  const float4 b4 = *(const float4*)(b + lane * 4);
  ushort4 o;
  o.x = f2bf((v.x - mean) * r * g4.x + b4.x);
  o.y = f2bf((v.y - mean) * r * g4.y + b4.y);
  o.z = f2bf((v.z - mean) * r * g4.z + b4.z);
  o.w = f2bf((v.w - mean) * r * g4.w + b4.w);
  *(ushort4*)(y + (size_t)row * C_DIM + lane * 4) = o;
}

// ------------------------------------------------- fused fp32->bf16 weights
__global__ void cvt_kernel(const float* __restrict__ s0, const float* __restrict__ s1,
                           const float* __restrict__ s2, const float* __restrict__ s3,
                           ushort_t* __restrict__ dst)
{
  const int i = blockIdx.x * 256 + threadIdx.x;
  // segments: qkv_w 196608 | proj_w 65536 | fc1_w 262144 | fc2_w 262144
  float v;
  if (i < 196608) v = s0[i];
  else if (i < 262144) v = s1[i - 196608];
  else if (i < 524288) v = s2[i - 262144];
  else v = s3[i - 524288];
  dst[i] = f2bf(v);
}

// ---------------------------------------------------------------- MFMA GEMM
// Out[n][j] = sum_k A[n][k]*W[j][k] + bias[j] (+ epilogue). BK=32.
// EPI 0: cols<256 *= ATT_SCALE; bf16 out (qkv)
// EPI 1: + extra[n][j]; fp32 out (proj+skip, fc2+skip)
// EPI 2: tanh-gelu; bf16 out (fc1)
// 64x256 tile, 4 waves -> 32x128 quadrants, 2x8 16x16x32 MFMAs per K-step.
// Double-buffered K-loop; 20KB/buffer -> 40KB LDS -> 4 blocks/CU (TLP hides
// the per-step vmcnt drain). LDS chunk (r,kc): kc_lds = kc_g ^ (r&3),
// applied on BOTH sides: pre-swizzled global k-offset in staging, and
// read address kc_lds = qd ^ (r&3) with r&3 == rl&3 for all fragment rows.
// Epilogue: per-wave LDS transpose (8.5KB/wave) -> float4/ushort8 stores.
template <int EPI>
__global__ __launch_bounds__(256, 4) void mfma_gemm(
    const ushort_t* __restrict__ A, const ushort_t* __restrict__ W,
    const float* __restrict__ bias, const float* __restrict__ extra,
    void* __restrict__ OutV, int Kdim, int Jdim)
{
  __shared__ __align__(16) char smem[40960];  // 2 x (A 4KB + B 16KB); epi 34KB
  const int t = threadIdx.x;
  const int lane = t & 63;
  const int w = t >> 6;
  const int wm = w & 1;    // row half (32 rows)
  const int wn = w >> 1;   // col half (128 cols)
  const int rowbase = blockIdx.y * 64;
  const int colbase = blockIdx.x * 256;

  floatx4 acc[2][8] = {};

  // staging geometry: thread t owns A chunk t and B chunks h*256+t (h=0..3).
  // chunk c -> row c>>2, kc_lds c&3; source kc_g = (c&3) ^ ((c>>2)&3);
  // identical for all h since h*256 contributes 0 mod 4 to both fields.
  const int rt = t >> 2;                                // 0..63
  const int kgo = (((t & 3) ^ (rt & 3))) * 8;           // pre-swizzled k elems
  int growA = rowbase + rt;
  if (growA > N_NODES - 1) growA = N_NODES - 1;         // clamp tail rows

  const int rl = lane & 15;
  const int qd = lane >> 4;                             // 0..3
  const int soff = (qd ^ (rl & 3)) * 8;                 // read-side swizzle
                                                        // (r&3 == rl&3)

  const int nk = Kdim >> 5;

  {  // prologue: stage K-tile 0 into buf 0
    ushort_t* Ab = (ushort_t*)smem;
    ushort_t* Bb = Ab + 2048;
    gload16(A + (size_t)growA * Kdim + kgo, Ab + t * 8);
#pragma unroll
    for (int h = 0; h < 4; ++h)
      gload16(W + (size_t)(colbase + h * 64 + rt) * Kdim + kgo,
              Bb + (h * 256 + t) * 8);
  }
  __syncthreads();

  for (int kt = 0; kt < nk; ++kt) {
    const int cur = kt & 1;
    if (kt + 1 < nk) {  // stage next K-tile into the other buffer
      const int k0n = (kt + 1) << 5;
      ushort_t* Ab = (ushort_t*)smem + (cur ^ 1) * 10240;
      ushort_t* Bb = Ab + 2048;
      gload16(A + (size_t)growA * Kdim + k0n + kgo, Ab + t * 8);
#pragma unroll
      for (int h = 0; h < 4; ++h)
        gload16(W + (size_t)(colbase + h * 64 + rt) * Kdim + k0n + kgo,
                Bb + (h * 256 + t) * 8);
    }

    const ushort_t* As = (const ushort_t*)smem + cur * 10240;
    const ushort_t* Bs = As + 2048;
    short8 af0 = *(const short8*)(As + (wm * 32 + rl) * 32 + soff);
    short8 af1 = *(const short8*)(As + (wm * 32 + 16 + rl) * 32 + soff);
#pragma unroll
    for (int tn = 0; tn < 8; ++tn) {
      const short8 bfr =
          *(const short8*)(Bs + (wn * 128 + tn * 16 + rl) * 32 + soff);
      acc[0][tn] = __builtin_amdgcn_mfma_f32_16x16x32_bf16(af0, bfr, acc[0][tn], 0, 0, 0);
      acc[1][tn] = __builtin_amdgcn_mfma_f32_16x16x32_bf16(af1, bfr, acc[1][tn], 0, 0, 0);
    }
    __syncthreads();
  }

  // ---- epilogue: LDS transpose -> full-line vector stores ----
  const int rr = lane >> 4;        // 0..3 (row group in read phase)
  if (EPI == 1) {
    float* sc = (float*)smem + w * (32 * 68);  // 32 rows x stride 68 fp32
    const int c4 = (lane & 15) * 4;            // 0..60
#pragma unroll
    for (int p = 0; p < 2; ++p) {
      __syncthreads();
#pragma unroll
      for (int th = 0; th < 4; ++th) {
        const int tn = p * 4 + th;
#pragma unroll
        for (int tm = 0; tm < 2; ++tm)
#pragma unroll
          for (int r = 0; r < 4; ++r)
            sc[(tm * 16 + qd * 4 + r) * 68 + th * 16 + rl] = acc[tm][tn][r];
      }
      __syncthreads();
      const int col0 = colbase + wn * 128 + p * 64 + c4;
      const float4 b4 = *(const float4*)(bias + col0);
#pragma unroll
      for (int it = 0; it < 8; ++it) {
        const int lr = it * 4 + rr;
        const int grow = rowbase + wm * 32 + lr;
        if (grow >= N_NODES) continue;
        float4 v = *(const float4*)(sc + lr * 68 + c4);
        const float4 e4 = *(const float4*)(extra + (size_t)grow * Jdim + col0);
        v.x += b4.x + e4.x; v.y += b4.y + e4.y;
        v.z += b4.z + e4.z; v.w += b4.w + e4.w;
        *(float4*)((float*)OutV + (size_t)grow * Jdim + col0) = v;
      }
    }
  } else {
    __syncthreads();
    ushort_t* su = (ushort_t*)smem + w * (32 * 136);  // 32 rows x stride 136
#pragma unroll
    for (int tn = 0; tn < 8; ++tn) {
      const int col = colbase + wn * 128 + tn * 16 + rl;
      const float bv = bias[col];
#pragma unroll
      for (int tm = 0; tm < 2; ++tm)
#pragma unroll
        for (int r = 0; r < 4; ++r) {
          float v = acc[tm][tn][r] + bv;
          if (EPI == 0) {
            if (col < 256) v *= ATT_SCALE;
          } else {
            v = gelu_tanh(v);
          }
          su[(tm * 16 + qd * 4 + r) * 136 + tn * 16 + rl] = f2bf(v);
        }
    }
    __syncthreads();
    const int c8 = (lane & 15) * 8;
#pragma unroll
    for (int it = 0; it < 8; ++it) {
      const int lr = it * 4 + rr;
      const int grow = rowbase + wm * 32 + lr;
      if (grow >= N_NODES) continue;
      const uint4 v = *(const uint4*)(su + lr * 136 + c8);
      *(uint4*)((ushort_t*)OutV + (size_t)grow * Jdim + colbase + wn * 128 + c8) = v;
    }
  }
}

// ---------------------------------------------------------------- edge bucket
__global__ void hist_kernel(const int* __restrict__ idx0, int* __restrict__ counts)
{
  const int m = blockIdx.x * 256 + threadIdx.x;
  if (m < M_EDGES) atomicAdd(&counts[idx0[m]], 1);
}

__global__ __launch_bounds__(256) void scan1_kernel(const int* __restrict__ counts,
    int* __restrict__ offsets, int* __restrict__ bsums)
{
  __shared__ int tmp[256];
  const int t = threadIdx.x;
  const int i = blockIdx.x * 256 + t;
  const int v = (i < N_NODES) ? counts[i] : 0;
  int x = v;
  tmp[t] = x;
  __syncthreads();
#pragma unroll
  for (int off = 1; off < 256; off <<= 1) {
    const int a = (t >= off) ? tmp[t - off] : 0;
    __syncthreads();
    x += a;
    tmp[t] = x;
    __syncthreads();
  }
  if (i < N_NODES) offsets[i] = x - v;
  if (t == 255) bsums[blockIdx.x] = x;
}

__global__ __launch_bounds__(256) void scan2_kernel(int* __restrict__ bsums, int nb)
{
  __shared__ int tmp[256];
  const int t = threadIdx.x;
  const int v = (t < nb) ? bsums[t] : 0;
  int x = v;
  tmp[t] = x;
  __syncthreads();
#pragma unroll
  for (int off = 1; off < 256; off <<= 1) {
    const int a = (t >= off) ? tmp[t - off] : 0;
    __syncthreads();
    x += a;
    tmp[t] = x;
    __syncthreads();
  }
  if (t < nb) bsums[t] = x - v;
}

__global__ void scan3_kernel(int* __restrict__ offsets, const int* __restrict__ bsums)
{
  const int i = blockIdx.x * 256 + threadIdx.x;
  if (i < N_NODES) offsets[i] += bsums[blockIdx.x];
  if (i == 0) offsets[N_NODES] = M_EDGES;
}

__global__ void scatter_kernel(const int* __restrict__ idx0,
    const int* __restrict__ idx1, const int* __restrict__ offsets,
    int* __restrict__ cursor, int* __restrict__ srcs)
{
  const int m = blockIdx.x * 256 + threadIdx.x;
  if (m < M_EDGES) {
    const int n = idx0[m];
    const int p = offsets[n] + atomicAdd(&cursor[n], 1);
    srcs[p] = idx1[m];
  }
}

// ---------------------------------------------------------------- attention
// One node per wave. 32 lanes cooperatively hold one edge's K/V row:
// lane l<32 owns 8 dims (uint4) of head l>>2. Wave halves process alternating
// edges with independent online softmax, merged at the end via shfl_xor(32).
__global__ __launch_bounds__(256) void attn_kernel(
    const ushort_t* __restrict__ QKVh, const int* __restrict__ offsets,
    const int* __restrict__ srcs, ushort_t* __restrict__ AO)
{
  const int node = blockIdx.x * 4 + (threadIdx.x >> 6);
  if (node >= N_NODES) return;
  const int lane = threadIdx.x & 63;
  const int l32 = lane & 31;
  const int half = lane >> 5;
  const int start = offsets[node];
  const int end = offsets[node + 1];

  // Q fragment: 8 bf16 dims of head l32>>2 (Q pre-scaled by ATT_SCALE in GEMM)
  const uint4 qp = *(const uint4*)((const uint_t*)(QKVh + (size_t)node * 768) + l32 * 4);

  float m = NEG_BIG, s = 0.f;
  float o[8];
#pragma unroll
  for (int j = 0; j < 8; ++j) o[j] = 0.f;

  for (int e = start + half; e < end; e += 4) {
    const int eB = e + 2;
    const bool hasB = eB < end;
    const int sA = srcs[e];
    const int sB = srcs[hasB ? eB : e];
    const uint_t* rA = (const uint_t*)(QKVh + (size_t)sA * 768);
    const uint_t* rB = (const uint_t*)(QKVh + (size_t)sB * 768);
    const uint4 kA = *(const uint4*)(rA + 128 + l32 * 4);
    const uint4 kB = *(const uint4*)(rB + 128 + l32 * 4);
    const uint4 vA = *(const uint4*)(rA + 256 + l32 * 4);
    const uint4 vB = *(const uint4*)(rB + 256 + l32 * 4);

    float dA = bf_even(qp.x) * bf_even(kA.x) + bf_odd(qp.x) * bf_odd(kA.x)
             + bf_even(qp.y) * bf_even(kA.y) + bf_odd(qp.y) * bf_odd(kA.y)
             + bf_even(qp.z) * bf_even(kA.z) + bf_odd(qp.z) * bf_odd(kA.z)
             + bf_even(qp.w) * bf_even(kA.w) + bf_odd(qp.w) * bf_odd(kA.w);
    dA += __shfl_xor(dA, 1);
    dA += __shfl_xor(dA, 2);
    float dB = bf_even(qp.x) * bf_even(kB.x) + bf_odd(qp.x) * bf_odd(kB.x)
             + bf_even(qp.y) * bf_even(kB.y) + bf_odd(qp.y) * bf_odd(kB.y)
             + bf_even(qp.z) * bf_even(kB.z) + bf_odd(qp.z) * bf_odd(kB.z)
             + bf_even(qp.w) * bf_even(kB.w) + bf_odd(qp.w) * bf_odd(kB.w);
    dB += __shfl_xor(dB, 1);
    dB += __shfl_xor(dB, 2);

    const float lA = dA * LOG2E;
    const float lB = hasB ? dB * LOG2E : NEG_BIG;
    const float mn = fmaxf(m, fmaxf(lA, lB));
    const float fac = exp2f(m - mn);
    const float wA = exp2f(lA - mn);
    const float wB = hasB ? exp2f(lB - mn) : 0.f;
    m = mn;
    s = s * fac + wA + wB;
    o[0] = o[0] * fac + wA * bf_even(vA.x) + wB * bf_even(vB.x);
    o[1] = o[1] * fac + wA * bf_odd(vA.x)  + wB * bf_odd(vB.x);
    o[2] = o[2] * fac + wA * bf_even(vA.y) + wB * bf_even(vB.y);
    o[3] = o[3] * fac + wA * bf_odd(vA.y)  + wB * bf_odd(vB.y);
    o[4] = o[4] * fac + wA * bf_even(vA.z) + wB * bf_even(vB.z);
    o[5] = o[5] * fac + wA * bf_odd(vA.z)  + wB * bf_odd(vB.z);
    o[6] = o[6] * fac + wA * bf_even(vA.w) + wB * bf_even(vB.w);
    o[7] = o[7] * fac + wA * bf_odd(vA.w)  + wB * bf_odd(vB.w);
  }

  // merge the two halves' online softmax states
  const float mO = __shfl_xor(m, 32);
  const float sO = __shfl_xor(s, 32);
  const float mm = fmaxf(m, mO);
  const float fS = exp2f(m - mm);
  const float fO = exp2f(mO - mm);
  const float st = s * fS + sO * fO;
  float out[8];
#pragma unroll
  for (int j = 0; j < 8; ++j) out[j] = o[j] * fS + __shfl_xor(o[j], 32) * fO;

  const float inv = (end > start) ? 1.0f / st : 0.0f;
  if (lane < 32) {
    uint4 st4;
    st4.x = (uint_t)f2bf(out[0] * inv) | ((uint_t)f2bf(out[1] * inv) << 16);
    st4.y = (uint_t)f2bf(out[2] * inv) | ((uint_t)f2bf(out[3] * inv) << 16);
    st4.z = (uint_t)f2bf(out[4] * inv) | ((uint_t)f2bf(out[5] * inv) << 16);
    st4.w = (uint_t)f2bf(out[6] * inv) | ((uint_t)f2bf(out[7] * inv) << 16);
    *(uint4*)((uint_t*)(AO + (size_t)node * 256) + l32 * 4) = st4;
  }
}

// ---------------------------------------------------------------- launch
extern "C" void kernel_launch(void* const* d_in, const int* in_sizes, int n_in,
                              void* d_out, int out_size, void* d_ws,
                              size_t ws_size, hipStream_t stream)
{
  const float* feats  = (const float*)d_in[0];
  const int*   edge   = (const int*)d_in[2];
  const float* ln1_g  = (const float*)d_in[3];
  const float* ln1_b  = (const float*)d_in[4];
  const float* qkv_w  = (const float*)d_in[5];
  const float* qkv_b  = (const float*)d_in[6];
  const float* proj_w = (const float*)d_in[7];
  const float* proj_b = (const float*)d_in[8];
  const float* ln2_g  = (const float*)d_in[9];
  const float* ln2_b  = (const float*)d_in[10];
  const float* fc1_w  = (const float*)d_in[11];
  const float* fc1_b  = (const float*)d_in[12];
  const float* fc2_w  = (const float*)d_in[13];
  const float* fc2_b  = (const float*)d_in[14];
  float* out = (float*)d_out;

  ushort_t* Xb   = (ushort_t*)d_ws;                       // N*256 bf16
  ushort_t* QKVh = Xb + (size_t)N_NODES * 256;            // N*768 bf16
  ushort_t* AOb  = QKVh + (size_t)N_NODES * 768;          // N*256 bf16
  ushort_t* Hb   = QKVh;                                  // N*1024 overlay
  ushort_t* wb   = AOb + (size_t)N_NODES * 256;           // 786432 bf16
  ushort_t* qkv_wb  = wb;
  ushort_t* proj_wb = qkv_wb + 768 * 256;
  ushort_t* fc1_wb  = proj_wb + 256 * 256;
  ushort_t* fc2_wb  = fc1_wb + 1024 * 256;
  int* counts  = (int*)(fc2_wb + 256 * 1024);
  int* cursor  = counts + N_NODES;
  int* offsets = cursor + N_NODES;
  int* srcs    = offsets + N_NODES + 1;
  int* bsums   = srcs + M_EDGES;
  const size_t required = (size_t)((char*)(bsums + 256) - (char*)d_ws);
  if (ws_size < required) {
    hipMemsetAsync(d_out, 0, (size_t)out_size * sizeof(float), stream);
    return;
  }
  const int* idx0 = edge;
  const int* idx1 = edge + M_EDGES;
  const int rowTiles = (N_NODES + 63) / 64;      // 782
  const int scanBlocks = (N_NODES + 255) / 256;  // 196

  hipMemsetAsync(counts, 0, 2 * N_NODES * sizeof(int), stream);
  cvt_kernel<<<786432 / 256, 256, 0, stream>>>(qkv_w, proj_w, fc1_w, fc2_w, wb);

  ln_kernel<<<N_NODES / 4, 256, 0, stream>>>(feats, ln1_g, ln1_b, Xb);
  mfma_gemm<0><<<dim3(768 / 256, rowTiles), 256, 0, stream>>>(
      Xb, qkv_wb, qkv_b, nullptr, QKVh, 256, 768);
  hist_kernel<<<(M_EDGES + 255) / 256, 256, 0, stream>>>(idx0, counts);
  scan1_kernel<<<scanBlocks, 256, 0, stream>>>(counts, offsets, bsums);
  scan2_kernel<<<1, 256, 0, stream>>>(bsums, scanBlocks);
  scan3_kernel<<<scanBlocks, 256, 0, stream>>>(offsets, bsums);
  scatter_kernel<<<(M_EDGES + 255) / 256, 256, 0, stream>>>(idx0, idx1, offsets,
                                                            cursor, srcs);
  attn_kernel<<<N_NODES / 4, 256, 0, stream>>>(QKVh, offsets, srcs, AOb);
  mfma_gemm<1><<<dim3(256 / 256, rowTiles), 256, 0, stream>>>(
      AOb, proj_wb, proj_b, feats, out, 256, 256);
  ln_kernel<<<N_NODES / 4, 256, 0, stream>>>(out, ln2_g, ln2_b, Xb);
  mfma_gemm<2><<<dim3(1024 / 256, rowTiles), 256, 0, stream>>>(
      Xb, fc1_wb, fc1_b, nullptr, Hb, 256, 1024);
  mfma_gemm<1><<<dim3(256 / 256, rowTiles), 256, 0, stream>>>(
      Hb, fc2_wb, fc2_b, out, out, 1024, 256);
}

// Round 7
// 488.636 us; speedup vs baseline: 1.1527x; 1.0757x over previous
//
#include <hip/hip_runtime.h>
#include <hip/hip_bf16.h>
#include <cmath>

// TransformerBlock: N=50000, C=256, H=8, HD=32, M=800000 edges, HID=1024.
// Round 12: fp8 (OCP e4m3) K/V for attention — the gather is byte-bound
// (FETCH pinned at 386MB across 4 structural attn variants; L2-capacity
// misses on a 77MB working set with degree-16 reuse). cvt8_kernel packs
// K,V (bf16->e4m3, v_cvt_pk_fp8_f32) into KV8 == Xb overlay (both 25.6MB;
// Xb dead between qkv-GEMM and ln2). attn reads K/V 8B/lane, decodes with
// v_cvt_pk_f32_fp8. Halves gather bytes AND working set (K/V 25.6MB).
// Round-6 rebudget: GEMM family ~190-210us (not 380 as earlier guessed);
// GEMM structure left unchanged this round (BK=32 dbuf, 4 blocks/CU).
// ws: Xb/KV8 25.6MB | QKVh 76.8MB | AOb 25.6MB (QKVh+AOb reused as H)
//     | wb 1.6MB | int meta ~3.8MB => ~133.5MB.

#define N_NODES 50000
#define C_DIM 256
#define M_EDGES 800000
#define ATT_SCALE 0.17677669529663687f /* 32^-0.5 */
#define LN_EPS 1e-5f
#define LOG2E 1.4426950408889634f
#define NEG_BIG -3.0e38f

typedef unsigned int uint_t;
typedef unsigned short ushort_t;
typedef short short8 __attribute__((ext_vector_type(8)));
typedef float floatx4 __attribute__((ext_vector_type(4)));
typedef float floatx2 __attribute__((ext_vector_type(2)));

__device__ __forceinline__ ushort_t f2bf(float f) {
  uint_t u = __float_as_uint(f);
  return (ushort_t)((u + 0x7FFFu + ((u >> 16) & 1u)) >> 16);  // RNE
}
__device__ __forceinline__ float bf_even(uint_t u) { return __uint_as_float(u << 16); }
__device__ __forceinline__ float bf_odd(uint_t u) { return __uint_as_float(u & 0xFFFF0000u); }

__device__ __forceinline__ float gelu_tanh(float x) {
  // tanh-form gelu; |diff vs exact erf gelu| <= ~3e-3, within error budget
  const float u = 0.7978845608028654f * (x + 0.044715f * x * x * x);
  const float e = __expf(2.0f * u);
  const float t = 1.0f - 2.0f / (e + 1.0f);
  return 0.5f * x * (1.0f + t);
}

__device__ __forceinline__ void gload16(const void* g, void* l) {
  __builtin_amdgcn_global_load_lds(
      (const __attribute__((address_space(1))) void*)g,
      (__attribute__((address_space(3))) void*)l, 16, 0, 0);
}

// ---------------------------------------------------------------- LayerNorm
// One row per wave: 64 lanes x float4 = 256 floats. No LDS, no barriers.
__global__ __launch_bounds__(256) void ln_kernel(const float* __restrict__ x,
    const float* __restrict__ g, const float* __restrict__ b,
    ushort_t* __restrict__ y)
{
  const int row = blockIdx.x * 4 + (threadIdx.x >> 6);
  const int lane = threadIdx.x & 63;
  const float4 v = *(const float4*)(x + (size_t)row * C_DIM + lane * 4);
  float s = v.x + v.y + v.z + v.w;
  float s2 = v.x * v.x + v.y * v.y + v.z * v.z + v.w * v.w;
#pragma unroll
  for (int m = 1; m < 64; m <<= 1) {
    s += __shfl_xor(s, m);
    s2 += __shfl_xor(s2, m);
  }
  const float mean = s * (1.0f / 256.0f);
  const float var = fmaxf(s2 * (1.0f / 256.0f) - mean * mean, 0.0f);
  const float r = rsqrtf(var + LN_EPS);
  const float4 g4 = *(const float4*)(g + lane * 4);
  const float4 b4 = *(const float4*)(b + lane * 4);
  ushort4 o;
  o.x = f2bf((v.x - mean) * r * g4.x + b4.x);
  o.y = f2bf((v.y - mean) * r * g4.y + b4.y);
  o.z = f2bf((v.z - mean) * r * g4.z + b4.z);
  o.w = f2bf((v.w - mean) * r * g4.w + b4.w);
  *(ushort4*)(y + (size_t)row * C_DIM + lane * 4) = o;
}

// ------------------------------------------------- fused fp32->bf16 weights
__global__ void cvt_kernel(const float* __restrict__ s0, const float* __restrict__ s1,
                           const float* __restrict__ s2, const float* __restrict__ s3,
                           ushort_t* __restrict__ dst)
{
  const int i = blockIdx.x * 256 + threadIdx.x;
  // segments: qkv_w 196608 | proj_w 65536 | fc1_w 262144 | fc2_w 262144
  float v;
  if (i < 196608) v = s0[i];
  else if (i < 262144) v = s1[i - 196608];
  else if (i < 524288) v = s2[i - 262144];
  else v = s3[i - 524288];
  dst[i] = f2bf(v);
}

// -------------------------------------------- bf16 K/V -> fp8 e4m3 pack
// KV8[node][0:256) = K dims, [256:512) = V dims (1B each). Thread handles
// 8 dims: reads uint4 (8 bf16) from QKVh elems node*768+256+j8, packs with
// v_cvt_pk_fp8_f32 into uint2.
__global__ __launch_bounds__(256) void cvt8_kernel(
    const ushort_t* __restrict__ QKVh, unsigned char* __restrict__ KV8)
{
  const int i = blockIdx.x * 256 + threadIdx.x;  // N*64 threads
  const int node = i >> 6;
  const int j8 = (i & 63) * 8;
  const uint4 u = *(const uint4*)(QKVh + (size_t)node * 768 + 256 + j8);
  uint_t w0 = 0, w1 = 0;
  w0 = __builtin_amdgcn_cvt_pk_fp8_f32(bf_even(u.x), bf_odd(u.x), w0, false);
  w0 = __builtin_amdgcn_cvt_pk_fp8_f32(bf_even(u.y), bf_odd(u.y), w0, true);
  w1 = __builtin_amdgcn_cvt_pk_fp8_f32(bf_even(u.z), bf_odd(u.z), w1, false);
  w1 = __builtin_amdgcn_cvt_pk_fp8_f32(bf_even(u.w), bf_odd(u.w), w1, true);
  uint2 st; st.x = w0; st.y = w1;
  *(uint2*)(KV8 + (size_t)i * 8) = st;
}

// ---------------------------------------------------------------- MFMA GEMM
// Out[n][j] = sum_k A[n][k]*W[j][k] + bias[j] (+ epilogue). BK=32.
// EPI 0: cols<256 *= ATT_SCALE; bf16 out (qkv)
// EPI 1: + extra[n][j]; fp32 out (proj+skip, fc2+skip)
// EPI 2: tanh-gelu; bf16 out (fc1)
// 64x256 tile, 4 waves -> 32x128 quadrants, 2x8 16x16x32 MFMAs per K-step.
// Double-buffered K-loop; 20KB/buffer -> 40KB LDS -> 4 blocks/CU (TLP hides
// the per-step vmcnt drain). LDS chunk (r,kc): kc_lds = kc_g ^ (r&3), both
// sides: pre-swizzled global k-offset in staging, read kc = qd ^ (rl&3).
// Epilogue: per-wave LDS transpose (8.5KB/wave) -> float4/ushort8 stores.
template <int EPI>
__global__ __launch_bounds__(256, 4) void mfma_gemm(
    const ushort_t* __restrict__ A, const ushort_t* __restrict__ W,
    const float* __restrict__ bias, const float* __restrict__ extra,
    void* __restrict__ OutV, int Kdim, int Jdim)
{
  __shared__ __align__(16) char smem[40960];  // 2 x (A 4KB + B 16KB); epi 34KB
  const int t = threadIdx.x;
  const int lane = t & 63;
  const int w = t >> 6;
  const int wm = w & 1;    // row half (32 rows)
  const int wn = w >> 1;   // col half (128 cols)
  const int rowbase = blockIdx.y * 64;
  const int colbase = blockIdx.x * 256;

  floatx4 acc[2][8] = {};

  const int rt = t >> 2;                                // 0..63
  const int kgo = (((t & 3) ^ (rt & 3))) * 8;           // pre-swizzled k elems
  int growA = rowbase + rt;
  if (growA > N_NODES - 1) growA = N_NODES - 1;         // clamp tail rows

  const int rl = lane & 15;
  const int qd = lane >> 4;                             // 0..3
  const int soff = (qd ^ (rl & 3)) * 8;                 // read-side swizzle

  const int nk = Kdim >> 5;

  {  // prologue: stage K-tile 0 into buf 0
    ushort_t* Ab = (ushort_t*)smem;
    ushort_t* Bb = Ab + 2048;
    gload16(A + (size_t)growA * Kdim + kgo, Ab + t * 8);
#pragma unroll
    for (int h = 0; h < 4; ++h)
      gload16(W + (size_t)(colbase + h * 64 + rt) * Kdim + kgo,
              Bb + (h * 256 + t) * 8);
  }
  __syncthreads();

  for (int kt = 0; kt < nk; ++kt) {
    const int cur = kt & 1;
    if (kt + 1 < nk) {  // stage next K-tile into the other buffer
      const int k0n = (kt + 1) << 5;
      ushort_t* Ab = (ushort_t*)smem + (cur ^ 1) * 10240;
      ushort_t* Bb = Ab + 2048;
      gload16(A + (size_t)growA * Kdim + k0n + kgo, Ab + t * 8);
#pragma unroll
      for (int h = 0; h < 4; ++h)
        gload16(W + (size_t)(colbase + h * 64 + rt) * Kdim + k0n + kgo,
                Bb + (h * 256 + t) * 8);
    }

    const ushort_t* As = (const ushort_t*)smem + cur * 10240;
    const ushort_t* Bs = As + 2048;
    short8 af0 = *(const short8*)(As + (wm * 32 + rl) * 32 + soff);
    short8 af1 = *(const short8*)(As + (wm * 32 + 16 + rl) * 32 + soff);
#pragma unroll
    for (int tn = 0; tn < 8; ++tn) {
      const short8 bfr =
          *(const short8*)(Bs + (wn * 128 + tn * 16 + rl) * 32 + soff);
      acc[0][tn] = __builtin_amdgcn_mfma_f32_16x16x32_bf16(af0, bfr, acc[0][tn], 0, 0, 0);
      acc[1][tn] = __builtin_amdgcn_mfma_f32_16x16x32_bf16(af1, bfr, acc[1][tn], 0, 0, 0);
    }
    __syncthreads();
  }

  // ---- epilogue: LDS transpose -> full-line vector stores ----
  const int rr = lane >> 4;        // 0..3 (row group in read phase)
  if (EPI == 1) {
    float* sc = (float*)smem + w * (32 * 68);  // 32 rows x stride 68 fp32
    const int c4 = (lane & 15) * 4;            // 0..60
#pragma unroll
    for (int p = 0; p < 2; ++p) {
      __syncthreads();
#pragma unroll
      for (int th = 0; th < 4; ++th) {
        const int tn = p * 4 + th;
#pragma unroll
        for (int tm = 0; tm < 2; ++tm)
#pragma unroll
          for (int r = 0; r < 4; ++r)
            sc[(tm * 16 + qd * 4 + r) * 68 + th * 16 + rl] = acc[tm][tn][r];
      }
      __syncthreads();
      const int col0 = colbase + wn * 128 + p * 64 + c4;
      const float4 b4 = *(const float4*)(bias + col0);
#pragma unroll
      for (int it = 0; it < 8; ++it) {
        const int lr = it * 4 + rr;
        const int grow = rowbase + wm * 32 + lr;
        if (grow >= N_NODES) continue;
        float4 v = *(const float4*)(sc + lr * 68 + c4);
        const float4 e4 = *(const float4*)(extra + (size_t)grow * Jdim + col0);
        v.x += b4.x + e4.x; v.y += b4.y + e4.y;
        v.z += b4.z + e4.z; v.w += b4.w + e4.w;
        *(float4*)((float*)OutV + (size_t)grow * Jdim + col0) = v;
      }
    }
  } else {
    __syncthreads();
    ushort_t* su = (ushort_t*)smem + w * (32 * 136);  // 32 rows x stride 136
#pragma unroll
    for (int tn = 0; tn < 8; ++tn) {
      const int col = colbase + wn * 128 + tn * 16 + rl;
      const float bv = bias[col];
#pragma unroll
      for (int tm = 0; tm < 2; ++tm)
#pragma unroll
        for (int r = 0; r < 4; ++r) {
          float v = acc[tm][tn][r] + bv;
          if (EPI == 0) {
            if (col < 256) v *= ATT_SCALE;
          } else {
            v = gelu_tanh(v);
          }
          su[(tm * 16 + qd * 4 + r) * 136 + tn * 16 + rl] = f2bf(v);
        }
    }
    __syncthreads();
    const int c8 = (lane & 15) * 8;
#pragma unroll
    for (int it = 0; it < 8; ++it) {
      const int lr = it * 4 + rr;
      const int grow = rowbase + wm * 32 + lr;
      if (grow >= N_NODES) continue;
      const uint4 v = *(const uint4*)(su + lr * 136 + c8);
      *(uint4*)((ushort_t*)OutV + (size_t)grow * Jdim + colbase + wn * 128 + c8) = v;
    }
  }
}

// ---------------------------------------------------------------- edge bucket
__global__ void hist_kernel(const int* __restrict__ idx0, int* __restrict__ counts)
{
  const int m = blockIdx.x * 256 + threadIdx.x;
  if (m < M_EDGES) atomicAdd(&counts[idx0[m]], 1);
}

__global__ __launch_bounds__(256) void scan1_kernel(const int* __restrict__ counts,
    int* __restrict__ offsets, int* __restrict__ bsums)
{
  __shared__ int tmp[256];
  const int t = threadIdx.x;
  const int i = blockIdx.x * 256 + t;
  const int v = (i < N_NODES) ? counts[i] : 0;
  int x = v;
  tmp[t] = x;
  __syncthreads();
#pragma unroll
  for (int off = 1; off < 256; off <<= 1) {
    const int a = (t >= off) ? tmp[t - off] : 0;
    __syncthreads();
    x += a;
    tmp[t] = x;
    __syncthreads();
  }
  if (i < N_NODES) offsets[i] = x - v;
  if (t == 255) bsums[blockIdx.x] = x;
}

__global__ __launch_bounds__(256) void scan2_kernel(int* __restrict__ bsums, int nb)
{
  __shared__ int tmp[256];
  const int t = threadIdx.x;
  const int v = (t < nb) ? bsums[t] : 0;
  int x = v;
  tmp[t] = x;
  __syncthreads();
#pragma unroll
  for (int off = 1; off < 256; off <<= 1) {
    const int a = (t >= off) ? tmp[t - off] : 0;
    __syncthreads();
    x += a;
    tmp[t] = x;
    __syncthreads();
  }
  if (t < nb) bsums[t] = x - v;
}

__global__ void scan3_kernel(int* __restrict__ offsets, const int* __restrict__ bsums)
{
  const int i = blockIdx.x * 256 + threadIdx.x;
  if (i < N_NODES) offsets[i] += bsums[blockIdx.x];
  if (i == 0) offsets[N_NODES] = M_EDGES;
}

__global__ void scatter_kernel(const int* __restrict__ idx0,
    const int* __restrict__ idx1, const int* __restrict__ offsets,
    int* __restrict__ cursor, int* __restrict__ srcs)
{
  const int m = blockIdx.x * 256 + threadIdx.x;
  if (m < M_EDGES) {
    const int n = idx0[m];
    const int p = offsets[n] + atomicAdd(&cursor[n], 1);
    srcs[p] = idx1[m];
  }
}

// ---------------------------------------------------------------- attention
// One node per wave. 32 lanes cooperatively hold one edge's K/V row (fp8
// e4m3, 8B/lane): lane l<32 owns 8 dims of head l>>2. Wave halves process
// alternating edges with independent online softmax, merged via shfl_xor(32).
// Q stays bf16 (pre-scaled by ATT_SCALE in qkv GEMM), pre-decoded to f32.
__global__ __launch_bounds__(256) void attn_kernel(
    const ushort_t* __restrict__ QKVh, const unsigned char* __restrict__ KV8,
    const int* __restrict__ offsets, const int* __restrict__ srcs,
    ushort_t* __restrict__ AO)
{
  const int node = blockIdx.x * 4 + (threadIdx.x >> 6);
  if (node >= N_NODES) return;
  const int lane = threadIdx.x & 63;
  const int l32 = lane & 31;
  const int half = lane >> 5;
  const int start = offsets[node];
  const int end = offsets[node + 1];

  float qf[8];
  {
    const uint4 qp = *(const uint4*)((const uint_t*)(QKVh + (size_t)node * 768) + l32 * 4);
    qf[0] = bf_even(qp.x); qf[1] = bf_odd(qp.x);
    qf[2] = bf_even(qp.y); qf[3] = bf_odd(qp.y);
    qf[4] = bf_even(qp.z); qf[5] = bf_odd(qp.z);
    qf[6] = bf_even(qp.w); qf[7] = bf_odd(qp.w);
  }

  float m = NEG_BIG, s = 0.f;
  float o[8];
#pragma unroll
  for (int j = 0; j < 8; ++j) o[j] = 0.f;

  for (int e = start + half; e < end; e += 4) {
    const int eB = e + 2;
    const bool hasB = eB < end;
    const int sA = srcs[e];
    const int sB = srcs[hasB ? eB : e];
    const uint2 kA = *(const uint2*)(KV8 + (size_t)sA * 512 + l32 * 8);
    const uint2 kB = *(const uint2*)(KV8 + (size_t)sB * 512 + l32 * 8);
    const uint2 vA = *(const uint2*)(KV8 + (size_t)sA * 512 + 256 + l32 * 8);
    const uint2 vB = *(const uint2*)(KV8 + (size_t)sB * 512 + 256 + l32 * 8);

    const floatx2 a0 = __builtin_amdgcn_cvt_pk_f32_fp8(kA.x, false);
    const floatx2 a1 = __builtin_amdgcn_cvt_pk_f32_fp8(kA.x, true);
    const floatx2 a2 = __builtin_amdgcn_cvt_pk_f32_fp8(kA.y, false);
    const floatx2 a3 = __builtin_amdgcn_cvt_pk_f32_fp8(kA.y, true);
    float dA = qf[0] * a0.x + qf[1] * a0.y + qf[2] * a1.x + qf[3] * a1.y
             + qf[4] * a2.x + qf[5] * a2.y + qf[6] * a3.x + qf[7] * a3.y;
    dA += __shfl_xor(dA, 1);
    dA += __shfl_xor(dA, 2);
    const floatx2 b0 = __builtin_amdgcn_cvt_pk_f32_fp8(kB.x, false);
    const floatx2 b1 = __builtin_amdgcn_cvt_pk_f32_fp8(kB.x, true);
    const floatx2 b2 = __builtin_amdgcn_cvt_pk_f32_fp8(kB.y, false);
    const floatx2 b3 = __builtin_amdgcn_cvt_pk_f32_fp8(kB.y, true);
    float dB = qf[0] * b0.x + qf[1] * b0.y + qf[2] * b1.x + qf[3] * b1.y
             + qf[4] * b2.x + qf[5] * b2.y + qf[6] * b3.x + qf[7] * b3.y;
    dB += __shfl_xor(dB, 1);
    dB += __shfl_xor(dB, 2);

    const float lA = dA * LOG2E;
    const float lB = hasB ? dB * LOG2E : NEG_BIG;
    const float mn = fmaxf(m, fmaxf(lA, lB));
    const float fac = exp2f(m - mn);
    const float wA = exp2f(lA - mn);
    const float wB = hasB ? exp2f(lB - mn) : 0.f;
    m = mn;
    s = s * fac + wA + wB;

    const floatx2 u0 = __builtin_amdgcn_cvt_pk_f32_fp8(vA.x, false);
    const floatx2 u1 = __builtin_amdgcn_cvt_pk_f32_fp8(vA.x, true);
    const floatx2 u2 = __builtin_amdgcn_cvt_pk_f32_fp8(vA.y, false);
    const floatx2 u3 = __builtin_amdgcn_cvt_pk_f32_fp8(vA.y, true);
    const floatx2 w0 = __builtin_amdgcn_cvt_pk_f32_fp8(vB.x, false);
    const floatx2 w1 = __builtin_amdgcn_cvt_pk_f32_fp8(vB.x, true);
    const floatx2 w2 = __builtin_amdgcn_cvt_pk_f32_fp8(vB.y, false);
    const floatx2 w3 = __builtin_amdgcn_cvt_pk_f32_fp8(vB.y, true);
    o[0] = o[0] * fac + wA * u0.x + wB * w0.x;
    o[1] = o[1] * fac + wA * u0.y + wB * w0.y;
    o[2] = o[2] * fac + wA * u1.x + wB * w1.x;
    o[3] = o[3] * fac + wA * u1.y + wB * w1.y;
    o[4] = o[4] * fac + wA * u2.x + wB * w2.x;
    o[5] = o[5] * fac + wA * u2.y + wB * w2.y;
    o[6] = o[6] * fac + wA * u3.x + wB * w3.x;
    o[7] = o[7] * fac + wA * u3.y + wB * w3.y;
  }

  // merge the two halves' online softmax states
  const float mO = __shfl_xor(m, 32);
  const float sO = __shfl_xor(s, 32);
  const float mm = fmaxf(m, mO);
  const float fS = exp2f(m - mm);
  const float fO = exp2f(mO - mm);
  const float st = s * fS + sO * fO;
  float out[8];
#pragma unroll
  for (int j = 0; j < 8; ++j) out[j] = o[j] * fS + __shfl_xor(o[j], 32) * fO;

  const float inv = (end > start) ? 1.0f / st : 0.0f;
  if (lane < 32) {
    uint4 st4;
    st4.x = (uint_t)f2bf(out[0] * inv) | ((uint_t)f2bf(out[1] * inv) << 16);
    st4.y = (uint_t)f2bf(out[2] * inv) | ((uint_t)f2bf(out[3] * inv) << 16);
    st4.z = (uint_t)f2bf(out[4] * inv) | ((uint_t)f2bf(out[5] * inv) << 16);
    st4.w = (uint_t)f2bf(out[6] * inv) | ((uint_t)f2bf(out[7] * inv) << 16);
    *(uint4*)((uint_t*)(AO + (size_t)node * 256) + l32 * 4) = st4;
  }
}

// ---------------------------------------------------------------- launch
extern "C" void kernel_launch(void* const* d_in, const int* in_sizes, int n_in,
                              void* d_out, int out_size, void* d_ws,
                              size_t ws_size, hipStream_t stream)
{
  const float* feats  = (const float*)d_in[0];
  const int*   edge   = (const int*)d_in[2];
  const float* ln1_g  = (const float*)d_in[3];
  const float* ln1_b  = (const float*)d_in[4];
  const float* qkv_w  = (const float*)d_in[5];
  const float* qkv_b  = (const float*)d_in[6];
  const float* proj_w = (const float*)d_in[7];
  const float* proj_b = (const float*)d_in[8];
  const float* ln2_g  = (const float*)d_in[9];
  const float* ln2_b  = (const float*)d_in[10];
  const float* fc1_w  = (const float*)d_in[11];
  const float* fc1_b  = (const float*)d_in[12];
  const float* fc2_w  = (const float*)d_in[13];
  const float* fc2_b  = (const float*)d_in[14];
  float* out = (float*)d_out;

  ushort_t* Xb   = (ushort_t*)d_ws;                       // N*256 bf16
  ushort_t* QKVh = Xb + (size_t)N_NODES * 256;            // N*768 bf16
  ushort_t* AOb  = QKVh + (size_t)N_NODES * 768;          // N*256 bf16
  ushort_t* Hb   = QKVh;                                  // N*1024 overlay
  unsigned char* KV8 = (unsigned char*)Xb;                // N*512 fp8 overlay
  ushort_t* wb   = AOb + (size_t)N_NODES * 256;           // 786432 bf16
  ushort_t* qkv_wb  = wb;
  ushort_t* proj_wb = qkv_wb + 768 * 256;
  ushort_t* fc1_wb  = proj_wb + 256 * 256;
  ushort_t* fc2_wb  = fc1_wb + 1024 * 256;
  int* counts  = (int*)(fc2_wb + 256 * 1024);
  int* cursor  = counts + N_NODES;
  int* offsets = cursor + N_NODES;
  int* srcs    = offsets + N_NODES + 1;
  int* bsums   = srcs + M_EDGES;
  const size_t required = (size_t)((char*)(bsums + 256) - (char*)d_ws);
  if (ws_size < required) {
    hipMemsetAsync(d_out, 0, (size_t)out_size * sizeof(float), stream);
    return;
  }
  const int* idx0 = edge;
  const int* idx1 = edge + M_EDGES;
  const int rowTiles = (N_NODES + 63) / 64;      // 782
  const int scanBlocks = (N_NODES + 255) / 256;  // 196

  hipMemsetAsync(counts, 0, 2 * N_NODES * sizeof(int), stream);
  cvt_kernel<<<786432 / 256, 256, 0, stream>>>(qkv_w, proj_w, fc1_w, fc2_w, wb);

  ln_kernel<<<N_NODES / 4, 256, 0, stream>>>(feats, ln1_g, ln1_b, Xb);
  mfma_gemm<0><<<dim3(768 / 256, rowTiles), 256, 0, stream>>>(
      Xb, qkv_wb, qkv_b, nullptr, QKVh, 256, 768);
  cvt8_kernel<<<(N_NODES * 64) / 256, 256, 0, stream>>>(QKVh, KV8);
  hist_kernel<<<(M_EDGES + 255) / 256, 256, 0, stream>>>(idx0, counts);
  scan1_kernel<<<scanBlocks, 256, 0, stream>>>(counts, offsets, bsums);
  scan2_kernel<<<1, 256, 0, stream>>>(bsums, scanBlocks);
  scan3_kernel<<<scanBlocks, 256, 0, stream>>>(offsets, bsums);
  scatter_kernel<<<(M_EDGES + 255) / 256, 256, 0, stream>>>(idx0, idx1, offsets,
                                                            cursor, srcs);
  attn_kernel<<<N_NODES / 4, 256, 0, stream>>>(QKVh, KV8, offsets, srcs, AOb);
  mfma_gemm<1><<<dim3(256 / 256, rowTiles), 256, 0, stream>>>(
      AOb, proj_wb, proj_b, feats, out, 256, 256);
  ln_kernel<<<N_NODES / 4, 256, 0, stream>>>(out, ln2_g, ln2_b, Xb);
  mfma_gemm<2><<<dim3(1024 / 256, rowTiles), 256, 0, stream>>>(
      Xb, fc1_wb, fc1_b, nullptr, Hb, 256, 1024);
  mfma_gemm<1><<<dim3(256 / 256, rowTiles), 256, 0, stream>>>(
      Hb, fc2_wb, fc2_b, out, out, 1024, 256);
}

// Round 9
// 475.891 us; speedup vs baseline: 1.1836x; 1.0268x over previous
//
#include <hip/hip_runtime.h>
#include <hip/hip_bf16.h>
#include <cmath>

// TransformerBlock: N=50000, C=256, H=8, HD=32, M=800000 edges, HID=1024.
// Round 14: resubmission of round-13 artifact unchanged — previous bench
// failed at container level (no timing, no counters, no correctness signal).
// Round 13: fc1 GEMM is VALU-bound (72us, VALUBusy 67%, MfmaUtil 14.6%,
// BANK_CONFLICT 4.4M). Two local fixes:
//  1. gelu: tanh-form with IEEE div (~30 VALU/val incl v_div_* sequence)
//     -> sigmoid form with v_rcp: x*rcp(1+exp2(-2u*log2e)) = 5 VALU+2 trans.
//  2. LDS layout: BK=32 row stride 64B made rows-2-apart alias (4-way
//     conflict per ds_read_b128). Pair-interleaved layout: chunk (r,kc) at
//     slot (r>>1)*8 + (r&1)*4 + (kc ^ ((r>>1)&3)) -> rows paired into full
//     128B wraps, reads 2-way (free). Desk-checked bijective + both-sides
//     consistent (W[130][k17] -> thread 11/h2 -> slot 523 both sides).
// Round-12 carry: fp8 K/V attn (worked: attn off top-5), BK=32 dbuf 40KB
// 4 blocks/CU, fp8 absmax 0.109 vs 0.144 threshold.
// ws: Xb/KV8 25.6MB | QKVh 76.8MB | AOb 25.6MB (QKVh+AOb reused as H)
//     | wb 1.6MB | int meta ~3.8MB => ~133.5MB.

#define N_NODES 50000
#define C_DIM 256
#define M_EDGES 800000
#define ATT_SCALE 0.17677669529663687f /* 32^-0.5 */
#define LN_EPS 1e-5f
#define LOG2E 1.4426950408889634f
#define NEG_BIG -3.0e38f

typedef unsigned int uint_t;
typedef unsigned short ushort_t;
typedef short short8 __attribute__((ext_vector_type(8)));
typedef float floatx4 __attribute__((ext_vector_type(4)));
typedef float floatx2 __attribute__((ext_vector_type(2)));

__device__ __forceinline__ ushort_t f2bf(float f) {
  uint_t u = __float_as_uint(f);
  return (ushort_t)((u + 0x7FFFu + ((u >> 16) & 1u)) >> 16);  // RNE
}
__device__ __forceinline__ float bf_even(uint_t u) { return __uint_as_float(u << 16); }
__device__ __forceinline__ float bf_odd(uint_t u) { return __uint_as_float(u & 0xFFFF0000u); }

__device__ __forceinline__ float gelu_fast(float x) {
  // tanh-gelu == x * sigmoid(2u), u = 0.79788456*(x + 0.044715 x^3).
  // exp2-form + v_rcp_f32 (1 ulp): 5 VALU + 2 trans, no IEEE divide.
  const float x2 = x * x;
  const float q = __builtin_fmaf(0.044715f, x2, 1.0f);
  const float z = x * q * -2.302208198f;  // -2*0.79788456*log2(e)
  const float e = exp2f(z);
  return x * __builtin_amdgcn_rcpf(e + 1.0f);
}

__device__ __forceinline__ void gload16(const void* g, void* l) {
  __builtin_amdgcn_global_load_lds(
      (const __attribute__((address_space(1))) void*)g,
      (__attribute__((address_space(3))) void*)l, 16, 0, 0);
}

// ---------------------------------------------------------------- LayerNorm
// One row per wave: 64 lanes x float4 = 256 floats. No LDS, no barriers.
__global__ __launch_bounds__(256) void ln_kernel(const float* __restrict__ x,
    const float* __restrict__ g, const float* __restrict__ b,
    ushort_t* __restrict__ y)
{
  const int row = blockIdx.x * 4 + (threadIdx.x >> 6);
  const int lane = threadIdx.x & 63;
  const float4 v = *(const float4*)(x + (size_t)row * C_DIM + lane * 4);
  float s = v.x + v.y + v.z + v.w;
  float s2 = v.x * v.x + v.y * v.y + v.z * v.z + v.w * v.w;
#pragma unroll
  for (int m = 1; m < 64; m <<= 1) {
    s += __shfl_xor(s, m);
    s2 += __shfl_xor(s2, m);
  }
  const float mean = s * (1.0f / 256.0f);
  const float var = fmaxf(s2 * (1.0f / 256.0f) - mean * mean, 0.0f);
  const float r = rsqrtf(var + LN_EPS);
  const float4 g4 = *(const float4*)(g + lane * 4);
  const float4 b4 = *(const float4*)(b + lane * 4);
  ushort4 o;
  o.x = f2bf((v.x - mean) * r * g4.x + b4.x);
  o.y = f2bf((v.y - mean) * r * g4.y + b4.y);
  o.z = f2bf((v.z - mean) * r * g4.z + b4.z);
  o.w = f2bf((v.w - mean) * r * g4.w + b4.w);
  *(ushort4*)(y + (size_t)row * C_DIM + lane * 4) = o;
}

// ------------------------------------------------- fused fp32->bf16 weights
__global__ void cvt_kernel(const float* __restrict__ s0, const float* __restrict__ s1,
                           const float* __restrict__ s2, const float* __restrict__ s3,
                           ushort_t* __restrict__ dst)
{
  const int i = blockIdx.x * 256 + threadIdx.x;
  // segments: qkv_w 196608 | proj_w 65536 | fc1_w 262144 | fc2_w 262144
  float v;
  if (i < 196608) v = s0[i];
  else if (i < 262144) v = s1[i - 196608];
  else if (i < 524288) v = s2[i - 262144];
  else v = s3[i - 524288];
  dst[i] = f2bf(v);
}

// -------------------------------------------- bf16 K/V -> fp8 e4m3 pack
// KV8[node][0:256) = K dims, [256:512) = V dims (1B each).
__global__ __launch_bounds__(256) void cvt8_kernel(
    const ushort_t* __restrict__ QKVh, unsigned char* __restrict__ KV8)
{
  const int i = blockIdx.x * 256 + threadIdx.x;  // N*64 threads
  const int node = i >> 6;
  const int j8 = (i & 63) * 8;
  const uint4 u = *(const uint4*)(QKVh + (size_t)node * 768 + 256 + j8);
  uint_t w0 = 0, w1 = 0;
  w0 = __builtin_amdgcn_cvt_pk_fp8_f32(bf_even(u.x), bf_odd(u.x), w0, false);
  w0 = __builtin_amdgcn_cvt_pk_fp8_f32(bf_even(u.y), bf_odd(u.y), w0, true);
  w1 = __builtin_amdgcn_cvt_pk_fp8_f32(bf_even(u.z), bf_odd(u.z), w1, false);
  w1 = __builtin_amdgcn_cvt_pk_fp8_f32(bf_even(u.w), bf_odd(u.w), w1, true);
  uint2 st; st.x = w0; st.y = w1;
  *(uint2*)(KV8 + (size_t)i * 8) = st;
}

// ---------------------------------------------------------------- MFMA GEMM
// Out[n][j] = sum_k A[n][k]*W[j][k] + bias[j] (+ epilogue). BK=32.
// EPI 0: cols<256 *= ATT_SCALE; bf16 out (qkv)
// EPI 1: + extra[n][j]; fp32 out (proj+skip, fc2+skip)
// EPI 2: sigmoid-gelu; bf16 out (fc1)
// 64x256 tile, 4 waves -> 32x128 quadrants, 2x8 16x16x32 MFMAs per K-step.
// Double-buffered K-loop; 20KB/buffer -> 40KB LDS -> 4 blocks/CU.
// LDS pair-interleaved layout: chunk (r,kc) at 16B-slot
//   (r>>1)*8 + (r&1)*4 + (kc ^ ((r>>1)&3))
// -> rows paired into 128B wraps, ds_read_b128 2-way (free) conflicts.
// Staging inverse (thread t, group h): r = h*64 + ((t>>3)<<1 | (t>>2)&1),
// kc = (t&3) ^ ((t>>3)&3); LDS dest stays linear (gload_lds requirement).
// Epilogue: per-wave LDS transpose (8.5KB/wave) -> float4/ushort8 stores.
template <int EPI>
__global__ __launch_bounds__(256, 4) void mfma_gemm(
    const ushort_t* __restrict__ A, const ushort_t* __restrict__ W,
    const float* __restrict__ bias, const float* __restrict__ extra,
    void* __restrict__ OutV, int Kdim, int Jdim)
{
  __shared__ __align__(16) char smem[40960];  // 2 x (A 4KB + B 16KB); epi 34KB
  const int t = threadIdx.x;
  const int lane = t & 63;
  const int w = t >> 6;
  const int wm = w & 1;    // row half (32 rows)
  const int wn = w >> 1;   // col half (128 cols)
  const int rowbase = blockIdx.y * 64;
  const int colbase = blockIdx.x * 256;

  floatx4 acc[2][8] = {};

  // staging geometry (pair-interleaved): thread t owns LDS chunk h*256+t.
  const int rloc = ((t >> 3) << 1) | ((t >> 2) & 1);    // 0..63
  const int kgo = ((t & 3) ^ ((t >> 3) & 3)) * 8;       // source k elems
  int growA = rowbase + rloc;
  if (growA > N_NODES - 1) growA = N_NODES - 1;         // clamp tail rows

  const int rl = lane & 15;
  const int qd = lane >> 4;                             // 0..3 (k-chunk)
  const int rh = rl >> 1;
  // per-lane fixed part of read address (ushorts): 64B-half + swizzled slot
  const int lfix = (rl & 1) * 32 + ((qd ^ (rh & 3)) * 8);

  const int nk = Kdim >> 5;

  {  // prologue: stage K-tile 0 into buf 0
    ushort_t* Ab = (ushort_t*)smem;
    ushort_t* Bb = Ab + 2048;
    gload16(A + (size_t)growA * Kdim + kgo, Ab + t * 8);
#pragma unroll
    for (int h = 0; h < 4; ++h)
      gload16(W + (size_t)(colbase + h * 64 + rloc) * Kdim + kgo,
              Bb + (h * 256 + t) * 8);
  }
  __syncthreads();

  for (int kt = 0; kt < nk; ++kt) {
    const int cur = kt & 1;
    if (kt + 1 < nk) {  // stage next K-tile into the other buffer
      const int k0n = (kt + 1) << 5;
      ushort_t* Ab = (ushort_t*)smem + (cur ^ 1) * 10240;
      ushort_t* Bb = Ab + 2048;
      gload16(A + (size_t)growA * Kdim + k0n + kgo, Ab + t * 8);
#pragma unroll
      for (int h = 0; h < 4; ++h)
        gload16(W + (size_t)(colbase + h * 64 + rloc) * Kdim + k0n + kgo,
                Bb + (h * 256 + t) * 8);
    }

    const ushort_t* As = (const ushort_t*)smem + cur * 10240;
    const ushort_t* Bs = As + 2048;
    short8 af0 = *(const short8*)(As + (wm * 16 + rh) * 64 + lfix);
    short8 af1 = *(const short8*)(As + (wm * 16 + 8 + rh) * 64 + lfix);
#pragma unroll
    for (int tn = 0; tn < 8; ++tn) {
      const short8 bfr =
          *(const short8*)(Bs + (wn * 64 + tn * 8 + rh) * 64 + lfix);
      acc[0][tn] = __builtin_amdgcn_mfma_f32_16x16x32_bf16(af0, bfr, acc[0][tn], 0, 0, 0);
      acc[1][tn] = __builtin_amdgcn_mfma_f32_16x16x32_bf16(af1, bfr, acc[1][tn], 0, 0, 0);
    }
    __syncthreads();
  }

  // ---- epilogue: LDS transpose -> full-line vector stores ----
  const int rr = lane >> 4;        // 0..3 (row group in read phase)
  if (EPI == 1) {
    float* sc = (float*)smem + w * (32 * 68);  // 32 rows x stride 68 fp32
    const int c4 = (lane & 15) * 4;            // 0..60
#pragma unroll
    for (int p = 0; p < 2; ++p) {
      __syncthreads();
#pragma unroll
      for (int th = 0; th < 4; ++th) {
        const int tn = p * 4 + th;
#pragma unroll
        for (int tm = 0; tm < 2; ++tm)
#pragma unroll
          for (int r = 0; r < 4; ++r)
            sc[(tm * 16 + qd * 4 + r) * 68 + th * 16 + rl] = acc[tm][tn][r];
      }
      __syncthreads();
      const int col0 = colbase + wn * 128 + p * 64 + c4;
      const float4 b4 = *(const float4*)(bias + col0);
#pragma unroll
      for (int it = 0; it < 8; ++it) {
        const int lr = it * 4 + rr;
        const int grow = rowbase + wm * 32 + lr;
        if (grow >= N_NODES) continue;
        float4 v = *(const float4*)(sc + lr * 68 + c4);
        const float4 e4 = *(const float4*)(extra + (size_t)grow * Jdim + col0);
        v.x += b4.x + e4.x; v.y += b4.y + e4.y;
        v.z += b4.z + e4.z; v.w += b4.w + e4.w;
        *(float4*)((float*)OutV + (size_t)grow * Jdim + col0) = v;
      }
    }
  } else {
    __syncthreads();
    ushort_t* su = (ushort_t*)smem + w * (32 * 136);  // 32 rows x stride 136
#pragma unroll
    for (int tn = 0; tn < 8; ++tn) {
      const int col = colbase + wn * 128 + tn * 16 + rl;
      const float bv = bias[col];
#pragma unroll
      for (int tm = 0; tm < 2; ++tm)
#pragma unroll
        for (int r = 0; r < 4; ++r) {
          float v = acc[tm][tn][r] + bv;
          if (EPI == 0) {
            if (col < 256) v *= ATT_SCALE;
          } else {
            v = gelu_fast(v);
          }
          su[(tm * 16 + qd * 4 + r) * 136 + tn * 16 + rl] = f2bf(v);
        }
    }
    __syncthreads();
    const int c8 = (lane & 15) * 8;
#pragma unroll
    for (int it = 0; it < 8; ++it) {
      const int lr = it * 4 + rr;
      const int grow = rowbase + wm * 32 + lr;
      if (grow >= N_NODES) continue;
      const uint4 v = *(const uint4*)(su + lr * 136 + c8);
      *(uint4*)((ushort_t*)OutV + (size_t)grow * Jdim + colbase + wn * 128 + c8) = v;
    }
  }
}

// ---------------------------------------------------------------- edge bucket
__global__ void hist_kernel(const int* __restrict__ idx0, int* __restrict__ counts)
{
  const int m = blockIdx.x * 256 + threadIdx.x;
  if (m < M_EDGES) atomicAdd(&counts[idx0[m]], 1);
}

__global__ __launch_bounds__(256) void scan1_kernel(const int* __restrict__ counts,
    int* __restrict__ offsets, int* __restrict__ bsums)
{
  __shared__ int tmp[256];
  const int t = threadIdx.x;
  const int i = blockIdx.x * 256 + t;
  const int v = (i < N_NODES) ? counts[i] : 0;
  int x = v;
  tmp[t] = x;
  __syncthreads();
#pragma unroll
  for (int off = 1; off < 256; off <<= 1) {
    const int a = (t >= off) ? tmp[t - off] : 0;
    __syncthreads();
    x += a;
    tmp[t] = x;
    __syncthreads();
  }
  if (i < N_NODES) offsets[i] = x - v;
  if (t == 255) bsums[blockIdx.x] = x;
}

__global__ __launch_bounds__(256) void scan2_kernel(int* __restrict__ bsums, int nb)
{
  __shared__ int tmp[256];
  const int t = threadIdx.x;
  const int v = (t < nb) ? bsums[t] : 0;
  int x = v;
  tmp[t] = x;
  __syncthreads();
#pragma unroll
  for (int off = 1; off < 256; off <<= 1) {
    const int a = (t >= off) ? tmp[t - off] : 0;
    __syncthreads();
    x += a;
    tmp[t] = x;
    __syncthreads();
  }
  if (t < nb) bsums[t] = x - v;
}

__global__ void scan3_kernel(int* __restrict__ offsets, const int* __restrict__ bsums)
{
  const int i = blockIdx.x * 256 + threadIdx.x;
  if (i < N_NODES) offsets[i] += bsums[blockIdx.x];
  if (i == 0) offsets[N_NODES] = M_EDGES;
}

__global__ void scatter_kernel(const int* __restrict__ idx0,
    const int* __restrict__ idx1, const int* __restrict__ offsets,
    int* __restrict__ cursor, int* __restrict__ srcs)
{
  const int m = blockIdx.x * 256 + threadIdx.x;
  if (m < M_EDGES) {
    const int n = idx0[m];
    const int p = offsets[n] + atomicAdd(&cursor[n], 1);
    srcs[p] = idx1[m];
  }
}

// ---------------------------------------------------------------- attention
// One node per wave. 32 lanes cooperatively hold one edge's K/V row (fp8
// e4m3, 8B/lane): lane l<32 owns 8 dims of head l>>2. Wave halves process
// alternating edges with independent online softmax, merged via shfl_xor(32).
// Q stays bf16 (pre-scaled by ATT_SCALE in qkv GEMM), pre-decoded to f32.
__global__ __launch_bounds__(256) void attn_kernel(
    const ushort_t* __restrict__ QKVh, const unsigned char* __restrict__ KV8,
    const int* __restrict__ offsets, const int* __restrict__ srcs,
    ushort_t* __restrict__ AO)
{
  const int node = blockIdx.x * 4 + (threadIdx.x >> 6);
  if (node >= N_NODES) return;
  const int lane = threadIdx.x & 63;
  const int l32 = lane & 31;
  const int half = lane >> 5;
  const int start = offsets[node];
  const int end = offsets[node + 1];

  float qf[8];
  {
    const uint4 qp = *(const uint4*)((const uint_t*)(QKVh + (size_t)node * 768) + l32 * 4);
    qf[0] = bf_even(qp.x); qf[1] = bf_odd(qp.x);
    qf[2] = bf_even(qp.y); qf[3] = bf_odd(qp.y);
    qf[4] = bf_even(qp.z); qf[5] = bf_odd(qp.z);
    qf[6] = bf_even(qp.w); qf[7] = bf_odd(qp.w);
  }

  float m = NEG_BIG, s = 0.f;
  float o[8];
#pragma unroll
  for (int j = 0; j < 8; ++j) o[j] = 0.f;

  for (int e = start + half; e < end; e += 4) {
    const int eB = e + 2;
    const bool hasB = eB < end;
    const int sA = srcs[e];
    const int sB = srcs[hasB ? eB : e];
    const uint2 kA = *(const uint2*)(KV8 + (size_t)sA * 512 + l32 * 8);
    const uint2 kB = *(const uint2*)(KV8 + (size_t)sB * 512 + l32 * 8);
    const uint2 vA = *(const uint2*)(KV8 + (size_t)sA * 512 + 256 + l32 * 8);
    const uint2 vB = *(const uint2*)(KV8 + (size_t)sB * 512 + 256 + l32 * 8);

    const floatx2 a0 = __builtin_amdgcn_cvt_pk_f32_fp8(kA.x, false);
    const floatx2 a1 = __builtin_amdgcn_cvt_pk_f32_fp8(kA.x, true);
    const floatx2 a2 = __builtin_amdgcn_cvt_pk_f32_fp8(kA.y, false);
    const floatx2 a3 = __builtin_amdgcn_cvt_pk_f32_fp8(kA.y, true);
    float dA = qf[0] * a0.x + qf[1] * a0.y + qf[2] * a1.x + qf[3] * a1.y
             + qf[4] * a2.x + qf[5] * a2.y + qf[6] * a3.x + qf[7] * a3.y;
    dA += __shfl_xor(dA, 1);
    dA += __shfl_xor(dA, 2);
    const floatx2 b0 = __builtin_amdgcn_cvt_pk_f32_fp8(kB.x, false);
    const floatx2 b1 = __builtin_amdgcn_cvt_pk_f32_fp8(kB.x, true);
    const floatx2 b2 = __builtin_amdgcn_cvt_pk_f32_fp8(kB.y, false);
    const floatx2 b3 = __builtin_amdgcn_cvt_pk_f32_fp8(kB.y, true);
    float dB = qf[0] * b0.x + qf[1] * b0.y + qf[2] * b1.x + qf[3] * b1.y
             + qf[4] * b2.x + qf[5] * b2.y + qf[6] * b3.x + qf[7] * b3.y;
    dB += __shfl_xor(dB, 1);
    dB += __shfl_xor(dB, 2);

    const float lA = dA * LOG2E;
    const float lB = hasB ? dB * LOG2E : NEG_BIG;
    const float mn = fmaxf(m, fmaxf(lA, lB));
    const float fac = exp2f(m - mn);
    const float wA = exp2f(lA - mn);
    const float wB = hasB ? exp2f(lB - mn) : 0.f;
    m = mn;
    s = s * fac + wA + wB;

    const floatx2 u0 = __builtin_amdgcn_cvt_pk_f32_fp8(vA.x, false);
    const floatx2 u1 = __builtin_amdgcn_cvt_pk_f32_fp8(vA.x, true);
    const floatx2 u2 = __builtin_amdgcn_cvt_pk_f32_fp8(vA.y, false);
    const floatx2 u3 = __builtin_amdgcn_cvt_pk_f32_fp8(vA.y, true);
    const floatx2 w0 = __builtin_amdgcn_cvt_pk_f32_fp8(vB.x, false);
    const floatx2 w1 = __builtin_amdgcn_cvt_pk_f32_fp8(vB.x, true);
    const floatx2 w2 = __builtin_amdgcn_cvt_pk_f32_fp8(vB.y, false);
    const floatx2 w3 = __builtin_amdgcn_cvt_pk_f32_fp8(vB.y, true);
    o[0] = o[0] * fac + wA * u0.x + wB * w0.x;
    o[1] = o[1] * fac + wA * u0.y + wB * w0.y;
    o[2] = o[2] * fac + wA * u1.x + wB * w1.x;
    o[3] = o[3] * fac + wA * u1.y + wB * w1.y;
    o[4] = o[4] * fac + wA * u2.x + wB * w2.x;
    o[5] = o[5] * fac + wA * u2.y + wB * w2.y;
    o[6] = o[6] * fac + wA * u3.x + wB * w3.x;
    o[7] = o[7] * fac + wA * u3.y + wB * w3.y;
  }

  // merge the two halves' online softmax states
  const float mO = __shfl_xor(m, 32);
  const float sO = __shfl_xor(s, 32);
  const float mm = fmaxf(m, mO);
  const float fS = exp2f(m - mm);
  const float fO = exp2f(mO - mm);
  const float st = s * fS + sO * fO;
  float out[8];
#pragma unroll
  for (int j = 0; j < 8; ++j) out[j] = o[j] * fS + __shfl_xor(o[j], 32) * fO;

  const float inv = (end > start) ? 1.0f / st : 0.0f;
  if (lane < 32) {
    uint4 st4;
    st4.x = (uint_t)f2bf(out[0] * inv) | ((uint_t)f2bf(out[1] * inv) << 16);
    st4.y = (uint_t)f2bf(out[2] * inv) | ((uint_t)f2bf(out[3] * inv) << 16);
    st4.z = (uint_t)f2bf(out[4] * inv) | ((uint_t)f2bf(out[5] * inv) << 16);
    st4.w = (uint_t)f2bf(out[6] * inv) | ((uint_t)f2bf(out[7] * inv) << 16);
    *(uint4*)((uint_t*)(AO + (size_t)node * 256) + l32 * 4) = st4;
  }
}

// ---------------------------------------------------------------- launch
extern "C" void kernel_launch(void* const* d_in, const int* in_sizes, int n_in,
                              void* d_out, int out_size, void* d_ws,
                              size_t ws_size, hipStream_t stream)
{
  const float* feats  = (const float*)d_in[0];
  const int*   edge   = (const int*)d_in[2];
  const float* ln1_g  = (const float*)d_in[3];
  const float* ln1_b  = (const float*)d_in[4];
  const float* qkv_w  = (const float*)d_in[5];
  const float* qkv_b  = (const float*)d_in[6];
  const float* proj_w = (const float*)d_in[7];
  const float* proj_b = (const float*)d_in[8];
  const float* ln2_g  = (const float*)d_in[9];
  const float* ln2_b  = (const float*)d_in[10];
  const float* fc1_w  = (const float*)d_in[11];
  const float* fc1_b  = (const float*)d_in[12];
  const float* fc2_w  = (const float*)d_in[13];
  const float* fc2_b  = (const float*)d_in[14];
  float* out = (float*)d_out;

  ushort_t* Xb   = (ushort_t*)d_ws;                       // N*256 bf16
  ushort_t* QKVh = Xb + (size_t)N_NODES * 256;            // N*768 bf16
  ushort_t* AOb  = QKVh + (size_t)N_NODES * 768;          // N*256 bf16
  ushort_t* Hb   = QKVh;                                  // N*1024 overlay
  unsigned char* KV8 = (unsigned char*)Xb;                // N*512 fp8 overlay
  ushort_t* wb   = AOb + (size_t)N_NODES * 256;           // 786432 bf16
  ushort_t* qkv_wb  = wb;
  ushort_t* proj_wb = qkv_wb + 768 * 256;
  ushort_t* fc1_wb  = proj_wb + 256 * 256;
  ushort_t* fc2_wb  = fc1_wb + 1024 * 256;
  int* counts  = (int*)(fc2_wb + 256 * 1024);
  int* cursor  = counts + N_NODES;
  int* offsets = cursor + N_NODES;
  int* srcs    = offsets + N_NODES + 1;
  int* bsums   = srcs + M_EDGES;
  const size_t required = (size_t)((char*)(bsums + 256) - (char*)d_ws);
  if (ws_size < required) {
    hipMemsetAsync(d_out, 0, (size_t)out_size * sizeof(float), stream);
    return;
  }
  const int* idx0 = edge;
  const int* idx1 = edge + M_EDGES;
  const int rowTiles = (N_NODES + 63) / 64;      // 782
  const int scanBlocks = (N_NODES + 255) / 256;  // 196

  hipMemsetAsync(counts, 0, 2 * N_NODES * sizeof(int), stream);
  cvt_kernel<<<786432 / 256, 256, 0, stream>>>(qkv_w, proj_w, fc1_w, fc2_w, wb);

  ln_kernel<<<N_NODES / 4, 256, 0, stream>>>(feats, ln1_g, ln1_b, Xb);
  mfma_gemm<0><<<dim3(768 / 256, rowTiles), 256, 0, stream>>>(
      Xb, qkv_wb, qkv_b, nullptr, QKVh, 256, 768);
  cvt8_kernel<<<(N_NODES * 64) / 256, 256, 0, stream>>>(QKVh, KV8);
  hist_kernel<<<(M_EDGES + 255) / 256, 256, 0, stream>>>(idx0, counts);
  scan1_kernel<<<scanBlocks, 256, 0, stream>>>(counts, offsets, bsums);
  scan2_kernel<<<1, 256, 0, stream>>>(bsums, scanBlocks);
  scan3_kernel<<<scanBlocks, 256, 0, stream>>>(offsets, bsums);
  scatter_kernel<<<(M_EDGES + 255) / 256, 256, 0, stream>>>(idx0, idx1, offsets,
                                                            cursor, srcs);
  attn_kernel<<<N_NODES / 4, 256, 0, stream>>>(QKVh, KV8, offsets, srcs, AOb);
  mfma_gemm<1><<<dim3(256 / 256, rowTiles), 256, 0, stream>>>(
      AOb, proj_wb, proj_b, feats, out, 256, 256);
  ln_kernel<<<N_NODES / 4, 256, 0, stream>>>(out, ln2_g, ln2_b, Xb);
  mfma_gemm<2><<<dim3(1024 / 256, rowTiles), 256, 0, stream>>>(
      Xb, fc1_wb, fc1_b, nullptr, Hb, 256, 1024);
  mfma_gemm<1><<<dim3(256 / 256, rowTiles), 256, 0, stream>>>(
      Hb, fc2_wb, fc2_b, out, out, 1024, 256);
}